// Round 6
// baseline (534.471 us; speedup 1.0000x reference)
//
#include <hip/hip_runtime.h>

// GraphSAGE_13993003450942 — round 6:
//  - fp8(e4m3) shadow copies of x and h1 for the aggregation gathers (halves
//    gather bytes; fp32 accumulate, bf16 agg outputs; GEMM paths stay bf16)
//  - k_edge: phase A is a raw copy (no packsum VALU); Gu/Gv summed in phase B

typedef float f32x4 __attribute__((ext_vector_type(4)));
typedef float f32x2 __attribute__((ext_vector_type(2)));
typedef __bf16 bf16x8 __attribute__((ext_vector_type(8)));

__device__ __forceinline__ unsigned short f2b(float f) {
    unsigned u = __float_as_uint(f);
    u = u + 0x7fffu + ((u >> 16) & 1u);   // RNE
    return (unsigned short)(u >> 16);
}
__device__ __forceinline__ float b2f(unsigned short s) {
    return __uint_as_float(((unsigned)s) << 16);
}
__device__ __forceinline__ float blo(unsigned x) { return b2f((unsigned short)(x & 0xffffu)); }
__device__ __forceinline__ float bhi(unsigned x) { return b2f((unsigned short)(x >> 16)); }
__device__ __forceinline__ int swz(int r, int g) { return (g + (r >> 1)) & 3; }
__device__ __forceinline__ unsigned char f2f8(float v) {
    return (unsigned char)(__builtin_amdgcn_cvt_pk_fp8_f32(v, v, 0, false) & 0xff);
}

// ---------------- CSR build ----------------

__global__ void k_count(const int* __restrict__ dst, int* __restrict__ cnt, int E) {
    int e = blockIdx.x * 256 + threadIdx.x;
    if (e < E) atomicAdd(&cnt[dst[e]], 1);
}

__global__ __launch_bounds__(1024) void k_scan(int* __restrict__ cnt_cursor,
                                               int* __restrict__ row_ptr, int n) {
    __shared__ int wsum[16];
    __shared__ int carry;
    int t = threadIdx.x, lane = t & 63, w = t >> 6;
    if (t == 0) carry = 0;
    __syncthreads();
    int nch = (n + 1023) >> 10;
    for (int ch = 0; ch < nch; ++ch) {
        int i = (ch << 10) + t;
        int v = (i < n) ? cnt_cursor[i] : 0;
        int s = v;
        #pragma unroll
        for (int off = 1; off < 64; off <<= 1) {
            int u = __shfl_up(s, off);
            if (lane >= off) s += u;
        }
        if (lane == 63) wsum[w] = s;
        __syncthreads();
        int wpre = 0;
        for (int j = 0; j < w; ++j) wpre += wsum[j];
        int incl = s + wpre;
        int base = carry;
        if (i < n) { int ex = base + incl - v; row_ptr[i] = ex; cnt_cursor[i] = ex; }
        __syncthreads();
        if (t == 1023) carry = base + incl;
    }
    __syncthreads();
    if (t == 0) row_ptr[n] = carry;
}

__global__ void k_scatter(const int* __restrict__ src, const int* __restrict__ dst,
                          int* __restrict__ cursor, int* __restrict__ bucket, int E) {
    int e = blockIdx.x * 256 + threadIdx.x;
    if (e < E) {
        int p = atomicAdd(&cursor[dst[e]], 1);
        bucket[p] = src[e];
    }
}

// ---------------- conversions / weight repack ----------------
// Wc1 [8][256][32] (Wl1|Wr1), Wc2 [16][256][32] (Wl2|Wr2),
// W1g [8][512][32] (rows 0-255: W1[:,0:256]; rows 256-511: W1[:,256:512]),
// WaF [16][64][8] bf16 A-fragments of W1a_pad (k<16: W1[:,512+k]; k==16: b1; else 0)

__global__ void k_convert_weights(const float* __restrict__ Wl1, const float* __restrict__ Wr1,
                                  const float* __restrict__ Wl2, const float* __restrict__ Wr2,
                                  const float* __restrict__ W1, const float* __restrict__ b1,
                                  unsigned short* __restrict__ Wc1,
                                  unsigned short* __restrict__ Wc2,
                                  unsigned short* __restrict__ W1g,
                                  unsigned short* __restrict__ WaF) {
    int idx = blockIdx.x * 256 + threadIdx.x;
    if (idx < 65536) {
        int c = idx >> 13, j = (idx >> 5) & 255, kk = idx & 31;
        float v = (c < 4) ? Wl1[j * 128 + c * 32 + kk] : Wr1[j * 128 + (c - 4) * 32 + kk];
        Wc1[idx] = f2b(v);
    } else if (idx < 65536 + 131072) {
        int i2 = idx - 65536;
        int c = i2 >> 13, j = (i2 >> 5) & 255, kk = i2 & 31;
        float v = (c < 8) ? Wl2[j * 256 + c * 32 + kk] : Wr2[j * 256 + (c - 8) * 32 + kk];
        Wc2[i2] = f2b(v);
    } else if (idx < 65536 + 131072 + 131072) {
        int i3 = idx - 65536 - 131072;
        int c = i3 >> 14, j = (i3 >> 5) & 511, kk = i3 & 31;
        float v = (j < 256) ? W1[(size_t)j * 528 + c * 32 + kk]
                            : W1[(size_t)(j - 256) * 528 + 256 + c * 32 + kk];
        W1g[i3] = f2b(v);
    } else if (idx < 65536 + 131072 + 131072 + 8192) {
        int i4 = idx - 65536 - 131072 - 131072;
        int mi = i4 >> 9, l = (i4 >> 3) & 63, j = i4 & 7;
        int m = mi * 16 + (l & 15);
        int k = (l >> 4) * 8 + j;
        float v = (k < 16) ? W1[(size_t)m * 528 + 512 + k] : (k == 16 ? b1[m] : 0.f);
        WaF[i4] = f2b(v);
    }
}

// x fp32 -> xb bf16 + xf8 e4m3 (2 elements per thread, packed byte-pair store)
__global__ void k_xconvert(const float* __restrict__ in, unsigned short* __restrict__ xb,
                           unsigned char* __restrict__ xf8, int n) {
    int j = (blockIdx.x * 256 + threadIdx.x) * 2;
    if (j < n) {
        float a = in[j], b = in[j + 1];
        xb[j] = f2b(a); xb[j + 1] = f2b(b);
        unsigned p = __builtin_amdgcn_cvt_pk_fp8_f32(a, b, 0, false);
        *reinterpret_cast<unsigned short*>(xf8 + j) = (unsigned short)(p & 0xffffu);
    }
}

// ---------------- aggregation (mean over in-neighbors, fp8 gather) ----------------

__device__ __forceinline__ void accf8(uint2 v, float* s) {
    f32x2 p0 = __builtin_amdgcn_cvt_pk_f32_fp8(v.x, false);
    f32x2 p1 = __builtin_amdgcn_cvt_pk_f32_fp8(v.x, true);
    f32x2 p2 = __builtin_amdgcn_cvt_pk_f32_fp8(v.y, false);
    f32x2 p3 = __builtin_amdgcn_cvt_pk_f32_fp8(v.y, true);
    s[0] += p0.x; s[1] += p0.y; s[2] += p1.x; s[3] += p1.y;
    s[4] += p2.x; s[5] += p2.y; s[6] += p3.x; s[7] += p3.y;
}

// xf8 [N][128]B; 4 subgroups x 16 lanes x 8B (full 128B row per subgroup instr)
__global__ __launch_bounds__(256) void k_agg_x(const unsigned char* __restrict__ xf8,
                                               const int* __restrict__ row_ptr,
                                               const int* __restrict__ bucket,
                                               unsigned short* __restrict__ agg, int Nn) {
    int node = blockIdx.x * 4 + (threadIdx.x >> 6);
    if (node >= Nn) return;
    int lane = threadIdx.x & 63;
    int q = lane >> 4, c = lane & 15;
    int beg = row_ptr[node], end = row_ptr[node + 1];
    int len = end - beg;
    int lo = beg + ((len * q) >> 2);
    int hi = beg + ((len * (q + 1)) >> 2);
    float s[8] = {0.f,0.f,0.f,0.f,0.f,0.f,0.f,0.f};
    const unsigned char* xp = xf8 + c * 8;
    int e = lo;
    for (; e + 4 <= hi; e += 4) {
        int b0 = bucket[e], b1 = bucket[e + 1], b2 = bucket[e + 2], b3 = bucket[e + 3];
        uint2 v0 = *reinterpret_cast<const uint2*>(xp + (size_t)b0 * 128);
        uint2 v1 = *reinterpret_cast<const uint2*>(xp + (size_t)b1 * 128);
        uint2 v2 = *reinterpret_cast<const uint2*>(xp + (size_t)b2 * 128);
        uint2 v3 = *reinterpret_cast<const uint2*>(xp + (size_t)b3 * 128);
        accf8(v0, s); accf8(v1, s); accf8(v2, s); accf8(v3, s);
    }
    for (; e < hi; ++e)
        accf8(*reinterpret_cast<const uint2*>(xp + (size_t)bucket[e] * 128), s);
    #pragma unroll
    for (int j = 0; j < 8; ++j) {
        s[j] += __shfl_xor(s[j], 16);
        s[j] += __shfl_xor(s[j], 32);
    }
    if (q == 0) {
        float sc = 1.0f / (float)(len > 1 ? len : 1);
        uint4 o;
        o.x = (unsigned)f2b(s[0]*sc) | ((unsigned)f2b(s[1]*sc) << 16);
        o.y = (unsigned)f2b(s[2]*sc) | ((unsigned)f2b(s[3]*sc) << 16);
        o.z = (unsigned)f2b(s[4]*sc) | ((unsigned)f2b(s[5]*sc) << 16);
        o.w = (unsigned)f2b(s[6]*sc) | ((unsigned)f2b(s[7]*sc) << 16);
        *reinterpret_cast<uint4*>(agg + (size_t)node * 128 + c * 8) = o;
    }
}

// h1f8 [N][256]B; 2 subgroups x 32 lanes x 8B (full 256B row per subgroup instr)
__global__ __launch_bounds__(256) void k_agg_h(const unsigned char* __restrict__ hf8,
                                               const int* __restrict__ row_ptr,
                                               const int* __restrict__ bucket,
                                               unsigned short* __restrict__ agg, int Nn) {
    int node = blockIdx.x * 4 + (threadIdx.x >> 6);
    if (node >= Nn) return;
    int lane = threadIdx.x & 63;
    int g = lane >> 5, c = lane & 31;
    int beg = row_ptr[node], end = row_ptr[node + 1];
    int len = end - beg;
    int lo = beg + ((len * g) >> 1);
    int hi = beg + ((len * (g + 1)) >> 1);
    float s[8] = {0.f,0.f,0.f,0.f,0.f,0.f,0.f,0.f};
    const unsigned char* hp = hf8 + c * 8;
    int e = lo;
    for (; e + 4 <= hi; e += 4) {
        int b0 = bucket[e], b1 = bucket[e + 1], b2 = bucket[e + 2], b3 = bucket[e + 3];
        uint2 v0 = *reinterpret_cast<const uint2*>(hp + (size_t)b0 * 256);
        uint2 v1 = *reinterpret_cast<const uint2*>(hp + (size_t)b1 * 256);
        uint2 v2 = *reinterpret_cast<const uint2*>(hp + (size_t)b2 * 256);
        uint2 v3 = *reinterpret_cast<const uint2*>(hp + (size_t)b3 * 256);
        accf8(v0, s); accf8(v1, s); accf8(v2, s); accf8(v3, s);
    }
    for (; e < hi; ++e)
        accf8(*reinterpret_cast<const uint2*>(hp + (size_t)bucket[e] * 256), s);
    #pragma unroll
    for (int j = 0; j < 8; ++j) s[j] += __shfl_xor(s[j], 32);
    if (g == 0) {
        float sc = 1.0f / (float)(len > 1 ? len : 1);
        uint4 o;
        o.x = (unsigned)f2b(s[0]*sc) | ((unsigned)f2b(s[1]*sc) << 16);
        o.y = (unsigned)f2b(s[2]*sc) | ((unsigned)f2b(s[3]*sc) << 16);
        o.z = (unsigned)f2b(s[4]*sc) | ((unsigned)f2b(s[5]*sc) << 16);
        o.w = (unsigned)f2b(s[6]*sc) | ((unsigned)f2b(s[7]*sc) << 16);
        *reinterpret_cast<uint4*>(agg + (size_t)node * 256 + c * 8) = o;
    }
}

// ---------------- conv GEMM: H = relu(bias + Aagg@Wl^T + Aself@Wr^T) ----------------
// bf16 out; optional fp8 shadow copy (Hf8 != nullptr) for the next agg's gather.

__global__ __launch_bounds__(256) void k_conv_gemm(const unsigned short* __restrict__ Aagg,
                                                   const unsigned short* __restrict__ Aself,
                                                   const unsigned short* __restrict__ Wck,
                                                   const float* __restrict__ bias,
                                                   unsigned short* __restrict__ Hout,
                                                   unsigned char* __restrict__ Hf8,
                                                   int Nn, int F) {
    __shared__ __align__(16) unsigned short zt[128 * 32];
    __shared__ __align__(16) unsigned short wt[128 * 32];
    const int t = threadIdx.x;
    const int lane = t & 63, w = t >> 6;
    const int wm = w >> 1, wn = w & 1;
    const int node0 = blockIdx.x * 128;
    const int colh = blockIdx.y;
    const int half = F >> 5, nchunks = F >> 4;

    f32x4 acc[4][4];
    #pragma unroll
    for (int i = 0; i < 4; ++i)
        #pragma unroll
        for (int j = 0; j < 4; ++j) acc[i][j] = (f32x4){0.f, 0.f, 0.f, 0.f};

    for (int c = 0; c < nchunks; ++c) {
        __syncthreads();
        const unsigned short* Asrc = (c < half) ? Aagg : Aself;
        const int ccol = ((c < half) ? c : c - half) * 32;
        #pragma unroll
        for (int p = 0; p < 2; ++p) {
            int fc = t + p * 256;
            int row = fc >> 2, seg = fc & 3;
            int node = node0 + row; if (node >= Nn) node = Nn - 1;
            uint4 v = *reinterpret_cast<const uint4*>(Asrc + (size_t)node * F + ccol + seg * 8);
            *reinterpret_cast<uint4*>(&zt[row * 32 + swz(row, seg) * 8]) = v;
        }
        const unsigned short* Wsrc = Wck + ((size_t)c * 256 + colh * 128) * 32;
        #pragma unroll
        for (int p = 0; p < 2; ++p) {
            int fc = t + p * 256;
            int row = fc >> 2, seg = fc & 3;
            *reinterpret_cast<uint4*>(&wt[row * 32 + swz(row, seg) * 8]) =
                *reinterpret_cast<const uint4*>(Wsrc + fc * 8);
        }
        __syncthreads();
        bf16x8 a[4], b[4];
        const int q = lane >> 4;
        #pragma unroll
        for (int mi = 0; mi < 4; ++mi) {
            int R = wm * 64 + mi * 16 + (lane & 15);
            a[mi] = *reinterpret_cast<const bf16x8*>(&zt[R * 32 + swz(R, q) * 8]);
        }
        #pragma unroll
        for (int ni = 0; ni < 4; ++ni) {
            int R = wn * 64 + ni * 16 + (lane & 15);
            b[ni] = *reinterpret_cast<const bf16x8*>(&wt[R * 32 + swz(R, q) * 8]);
        }
        #pragma unroll
        for (int mi = 0; mi < 4; ++mi)
            #pragma unroll
            for (int ni = 0; ni < 4; ++ni)
                acc[mi][ni] = __builtin_amdgcn_mfma_f32_16x16x32_bf16(a[mi], b[ni], acc[mi][ni], 0, 0, 0);
    }

    #pragma unroll
    for (int mi = 0; mi < 4; ++mi)
        #pragma unroll
        for (int ni = 0; ni < 4; ++ni) {
            int col = colh * 128 + wn * 64 + ni * 16 + (lane & 15);
            float bia = bias[col];
            #pragma unroll
            for (int r = 0; r < 4; ++r) {
                int row = node0 + wm * 64 + mi * 16 + ((lane >> 4) << 2) + r;
                if (row < Nn) {
                    float v = acc[mi][ni][r] + bia;
                    v = v > 0.f ? v : 0.f;
                    Hout[(size_t)row * 256 + col] = f2b(v);
                    if (Hf8) Hf8[(size_t)row * 256 + col] = f2f8(v);
                }
            }
        }
}

// ---------------- G GEMM: G2 = h2 @ [W1u;W1v]^T  ([N][512] bf16) ----------------

__global__ __launch_bounds__(256) void k_gemm_g(const unsigned short* __restrict__ A,
                                                const unsigned short* __restrict__ Wck,
                                                unsigned short* __restrict__ Gout,
                                                int Nn) {
    __shared__ __align__(16) unsigned short zt[128 * 32];
    __shared__ __align__(16) unsigned short wt[128 * 32];
    const int t = threadIdx.x;
    const int lane = t & 63, w = t >> 6;
    const int wm = w >> 1, wn = w & 1;
    const int node0 = blockIdx.x * 128;
    const int colg = blockIdx.y;

    f32x4 acc[4][4];
    #pragma unroll
    for (int i = 0; i < 4; ++i)
        #pragma unroll
        for (int j = 0; j < 4; ++j) acc[i][j] = (f32x4){0.f, 0.f, 0.f, 0.f};

    for (int c = 0; c < 8; ++c) {
        __syncthreads();
        #pragma unroll
        for (int p = 0; p < 2; ++p) {
            int fc = t + p * 256;
            int row = fc >> 2, seg = fc & 3;
            int node = node0 + row; if (node >= Nn) node = Nn - 1;
            uint4 v = *reinterpret_cast<const uint4*>(A + (size_t)node * 256 + c * 32 + seg * 8);
            *reinterpret_cast<uint4*>(&zt[row * 32 + swz(row, seg) * 8]) = v;
        }
        const unsigned short* Wsrc = Wck + ((size_t)c * 512 + colg * 128) * 32;
        #pragma unroll
        for (int p = 0; p < 2; ++p) {
            int fc = t + p * 256;
            int row = fc >> 2, seg = fc & 3;
            *reinterpret_cast<uint4*>(&wt[row * 32 + swz(row, seg) * 8]) =
                *reinterpret_cast<const uint4*>(Wsrc + fc * 8);
        }
        __syncthreads();
        bf16x8 a[4], b[4];
        const int q = lane >> 4;
        #pragma unroll
        for (int mi = 0; mi < 4; ++mi) {
            int R = wm * 64 + mi * 16 + (lane & 15);
            a[mi] = *reinterpret_cast<const bf16x8*>(&zt[R * 32 + swz(R, q) * 8]);
        }
        #pragma unroll
        for (int ni = 0; ni < 4; ++ni) {
            int R = wn * 64 + ni * 16 + (lane & 15);
            b[ni] = *reinterpret_cast<const bf16x8*>(&wt[R * 32 + swz(R, q) * 8]);
        }
        #pragma unroll
        for (int mi = 0; mi < 4; ++mi)
            #pragma unroll
            for (int ni = 0; ni < 4; ++ni)
                acc[mi][ni] = __builtin_amdgcn_mfma_f32_16x16x32_bf16(a[mi], b[ni], acc[mi][ni], 0, 0, 0);
    }

    #pragma unroll
    for (int mi = 0; mi < 4; ++mi)
        #pragma unroll
        for (int ni = 0; ni < 4; ++ni) {
            int col = colg * 128 + wn * 64 + ni * 16 + (lane & 15);
            #pragma unroll
            for (int r = 0; r < 4; ++r) {
                int row = node0 + wm * 64 + mi * 16 + ((lane >> 4) << 2) + r;
                if (row < Nn)
                    Gout[(size_t)row * 512 + col] = f2b(acc[mi][ni][r]);
            }
        }
}

// ---------------- edge kernel v3 ----------------
// Phase A: raw copy of Gu/Gv rows into LDS (no VALU), 2 edges per instruction.
// Phase B: MFMA attr-term + Gu+Gv sum + relu·W2 reduce in C-layout.

__global__ __launch_bounds__(256) void k_edge(const unsigned short* __restrict__ G2,
                                              const float* __restrict__ attr,
                                              const int* __restrict__ eu,
                                              const int* __restrict__ ev,
                                              const uint4* __restrict__ WaF,
                                              const float* __restrict__ W2,
                                              const float* __restrict__ b2,
                                              const float* __restrict__ logexp,
                                              float* __restrict__ out, int P) {
    __shared__ __align__(16) unsigned short attrT[64 * 40];
    __shared__ __align__(16) unsigned short guT[64 * 264];
    __shared__ __align__(16) unsigned short gvT[64 * 264];
    __shared__ float w2s[256];
    const int t = threadIdx.x;
    const int lane = t & 63, w = t >> 6;
    const int base = blockIdx.x * 64;

    // stage attr -> attrT (cols 0..15 attr, 16 = 1.0 (b1 row), 17..31 = 0)
    {
        int e = t >> 2, seg = t & 3;
        int eg = base + e; if (eg >= P) eg = P - 1;
        const float4 f = *reinterpret_cast<const float4*>(attr + (size_t)eg * 16 + seg * 4);
        uint2 o;
        o.x = (unsigned)f2b(f.x) | ((unsigned)f2b(f.y) << 16);
        o.y = (unsigned)f2b(f.z) | ((unsigned)f2b(f.w) << 16);
        *reinterpret_cast<uint2*>(&attrT[e * 40 + seg * 4]) = o;
    }
    if (t < 64) {
        uint2 z0; z0.x = 0x3f80u; z0.y = 0u;
        *reinterpret_cast<uint2*>(&attrT[t * 40 + 16]) = z0;
        uint2 z1; z1.x = 0u; z1.y = 0u;
        *reinterpret_cast<uint2*>(&attrT[t * 40 + 20]) = z1;
        uint4 z2; z2.x = z2.y = z2.z = z2.w = 0u;
        *reinterpret_cast<uint4*>(&attrT[t * 40 + 24]) = z2;
    }
    w2s[t] = W2[t];
    __syncthreads();

    // phase A: contiguous raw gather, 2 edges per instruction, zero VALU unpack
    {
        const int h = lane >> 5, c = lane & 31;
        #pragma unroll
        for (int i = 0; i < 8; ++i) {
            int el = w * 16 + 2 * i + h;
            int eg = base + el; if (eg >= P) eg = P - 1;
            int u = eu[eg], v = ev[eg];
            uint4 a = *reinterpret_cast<const uint4*>(G2 + (size_t)u * 512 + c * 8);
            uint4 bb = *reinterpret_cast<const uint4*>(G2 + (size_t)v * 512 + 256 + c * 8);
            *reinterpret_cast<uint4*>(&guT[el * 264 + c * 8]) = a;
            *reinterpret_cast<uint4*>(&gvT[el * 264 + c * 8]) = bb;
        }
    }

    // phase B: attr-term MFMA + combine (wave reads only rows it wrote)
    const int el = lane & 15, q = lane >> 4;
    const int grow = w * 16 + el;
    const bf16x8 bfrag = *reinterpret_cast<const bf16x8*>(&attrT[grow * 40 + q * 8]);
    float s = 0.f;
    #pragma unroll
    for (int mi = 0; mi < 16; ++mi) {
        const bf16x8 af = *reinterpret_cast<const bf16x8*>(&WaF[mi * 64 + lane]);
        f32x4 acc = __builtin_amdgcn_mfma_f32_16x16x32_bf16(af, bfrag, (f32x4){0.f,0.f,0.f,0.f}, 0, 0, 0);
        const uint2 gu2 = *reinterpret_cast<const uint2*>(&guT[grow * 264 + mi * 16 + q * 4]);
        const uint2 gv2 = *reinterpret_cast<const uint2*>(&gvT[grow * 264 + mi * 16 + q * 4]);
        const float4 w2v = *reinterpret_cast<const float4*>(&w2s[mi * 16 + q * 4]);
        float y0 = acc[0] + blo(gu2.x) + blo(gv2.x);
        float y1 = acc[1] + bhi(gu2.x) + bhi(gv2.x);
        float y2 = acc[2] + blo(gu2.y) + blo(gv2.y);
        float y3 = acc[3] + bhi(gu2.y) + bhi(gv2.y);
        s += (y0 > 0.f ? y0 : 0.f) * w2v.x;
        s += (y1 > 0.f ? y1 : 0.f) * w2v.y;
        s += (y2 > 0.f ? y2 : 0.f) * w2v.z;
        s += (y3 > 0.f ? y3 : 0.f) * w2v.w;
    }
    s += __shfl_xor(s, 16);
    s += __shfl_xor(s, 32);
    int eg = base + grow;
    if (q == 0 && eg < P)
        out[eg] = logexp[eg] + b2[0] + s;
}

// ---------------- launch ----------------

extern "C" void kernel_launch(void* const* d_in, const int* in_sizes, int n_in,
                              void* d_out, int out_size, void* d_ws, size_t ws_size,
                              hipStream_t stream) {
    const float* x      = (const float*)d_in[0];
    const int*   eidx   = (const int*)d_in[1];
    const int*   eu     = (const int*)d_in[2];
    const int*   ev     = (const int*)d_in[3];
    const float* attr   = (const float*)d_in[4];
    const float* logexp = (const float*)d_in[5];
    const float* Wl1    = (const float*)d_in[6];
    const float* bl1    = (const float*)d_in[7];
    const float* Wr1    = (const float*)d_in[8];
    const float* Wl2    = (const float*)d_in[9];
    const float* bl2    = (const float*)d_in[10];
    const float* Wr2    = (const float*)d_in[11];
    const float* W1     = (const float*)d_in[12];
    const float* b1     = (const float*)d_in[13];
    const float* W2     = (const float*)d_in[14];
    const float* b2     = (const float*)d_in[15];
    float* out = (float*)d_out;

    const int N = in_sizes[0] / 128;
    const int E = in_sizes[1] / 2;
    const int P = in_sizes[2];
    const int* src = eidx;
    const int* dst = eidx + E;

    char* ws = (char*)d_ws;
    size_t off = 0;
    auto alloc = [&](size_t bytes) -> void* {
        off = (off + 255) & ~(size_t)255;
        void* p = ws + off;
        off += bytes;
        return p;
    };
    int* row_ptr = (int*)alloc((size_t)(N + 1) * 4);
    int* cursor  = (int*)alloc((size_t)N * 4);
    int* bucket  = (int*)alloc((size_t)E * 4);
    unsigned short* h1 = (unsigned short*)alloc((size_t)N * 256 * 2);
    unsigned short* h2 = (unsigned short*)alloc((size_t)N * 256 * 2);
    char* shared_base = (char*)alloc((size_t)N * 512 * 2);
    unsigned short* xb   = (unsigned short*)shared_base;                         // N*128
    unsigned short* agg1 = (unsigned short*)(shared_base + (size_t)N * 128 * 2); // N*128
    unsigned short* agg2 = (unsigned short*)(shared_base + (size_t)N * 256 * 2); // N*256
    unsigned short* G2   = (unsigned short*)shared_base;                         // N*512
    unsigned char* xf8  = (unsigned char*)alloc((size_t)N * 128);
    unsigned char* h1f8 = (unsigned char*)alloc((size_t)N * 256);
    unsigned short* Wc1  = (unsigned short*)alloc((size_t)65536 * 2);
    unsigned short* Wc2  = (unsigned short*)alloc((size_t)131072 * 2);
    unsigned short* W1g  = (unsigned short*)alloc((size_t)131072 * 2);
    unsigned short* WaF  = (unsigned short*)alloc((size_t)8192 * 2);

    hipMemsetAsync(cursor, 0, (size_t)N * 4, stream);
    k_count<<<(E + 255) / 256, 256, 0, stream>>>(dst, cursor, E);
    k_scan<<<1, 1024, 0, stream>>>(cursor, row_ptr, N);
    k_scatter<<<(E + 255) / 256, 256, 0, stream>>>(src, dst, cursor, bucket, E);
    k_convert_weights<<<(65536 + 131072 + 131072 + 8192 + 255) / 256, 256, 0, stream>>>(
        Wl1, Wr1, Wl2, Wr2, W1, b1, Wc1, Wc2, W1g, WaF);
    k_xconvert<<<(N * 64 + 255) / 256, 256, 0, stream>>>(x, xb, xf8, N * 128);

    k_agg_x<<<(N + 3) / 4, 256, 0, stream>>>(xf8, row_ptr, bucket, agg1, N);
    dim3 gconv((N + 127) / 128, 2);
    k_conv_gemm<<<gconv, 256, 0, stream>>>(agg1, xb, Wc1, bl1, h1, h1f8, N, 128);
    k_agg_h<<<(N + 3) / 4, 256, 0, stream>>>(h1f8, row_ptr, bucket, agg2, N);
    k_conv_gemm<<<gconv, 256, 0, stream>>>(agg2, h1, Wc2, bl2, h2, (unsigned char*)nullptr, N, 256);

    dim3 gg((N + 127) / 128, 4);
    k_gemm_g<<<gg, 256, 0, stream>>>(h2, W1g, G2, N);
    k_edge<<<(P + 63) / 64, 256, 0, stream>>>(G2, attr, eu, ev, (const uint4*)WaF,
                                              W2, b2, logexp, out, P);
}

// Round 7
// 503.351 us; speedup vs baseline: 1.0618x; 1.0618x over previous
//
#include <hip/hip_runtime.h>

// GraphSAGE_13993003450942 — round 7:
//  k_edge v4: single summed-g LDS tile (cheap truncating bf16 add, 9 VALU/dword),
//  split into two half-feature passes -> 23.5 KB LDS -> 6 blocks/CU (24 waves).
//  eu/ev staged to LDS once. Aggs keep fp8 gather (round 6, numerically free).

typedef float f32x4 __attribute__((ext_vector_type(4)));
typedef float f32x2 __attribute__((ext_vector_type(2)));
typedef __bf16 bf16x8 __attribute__((ext_vector_type(8)));

__device__ __forceinline__ unsigned short f2b(float f) {
    unsigned u = __float_as_uint(f);
    u = u + 0x7fffu + ((u >> 16) & 1u);   // RNE
    return (unsigned short)(u >> 16);
}
__device__ __forceinline__ float b2f(unsigned short s) {
    return __uint_as_float(((unsigned)s) << 16);
}
__device__ __forceinline__ float blo(unsigned x) { return b2f((unsigned short)(x & 0xffffu)); }
__device__ __forceinline__ float bhi(unsigned x) { return b2f((unsigned short)(x >> 16)); }
// packed bf16 pair-add, truncating round (9 VALU ops/dword)
__device__ __forceinline__ unsigned padd(unsigned a, unsigned b) {
    float lo = __uint_as_float(a << 16) + __uint_as_float(b << 16);
    float hi = __uint_as_float(a & 0xffff0000u) + __uint_as_float(b & 0xffff0000u);
    return (__float_as_uint(hi) & 0xffff0000u) | (__float_as_uint(lo) >> 16);
}
__device__ __forceinline__ int swz(int r, int g) { return (g + (r >> 1)) & 3; }
__device__ __forceinline__ unsigned char f2f8(float v) {
    return (unsigned char)(__builtin_amdgcn_cvt_pk_fp8_f32(v, v, 0, false) & 0xff);
}

// ---------------- CSR build ----------------

__global__ void k_count(const int* __restrict__ dst, int* __restrict__ cnt, int E) {
    int e = blockIdx.x * 256 + threadIdx.x;
    if (e < E) atomicAdd(&cnt[dst[e]], 1);
}

__global__ __launch_bounds__(1024) void k_scan(int* __restrict__ cnt_cursor,
                                               int* __restrict__ row_ptr, int n) {
    __shared__ int wsum[16];
    __shared__ int carry;
    int t = threadIdx.x, lane = t & 63, w = t >> 6;
    if (t == 0) carry = 0;
    __syncthreads();
    int nch = (n + 1023) >> 10;
    for (int ch = 0; ch < nch; ++ch) {
        int i = (ch << 10) + t;
        int v = (i < n) ? cnt_cursor[i] : 0;
        int s = v;
        #pragma unroll
        for (int off = 1; off < 64; off <<= 1) {
            int u = __shfl_up(s, off);
            if (lane >= off) s += u;
        }
        if (lane == 63) wsum[w] = s;
        __syncthreads();
        int wpre = 0;
        for (int j = 0; j < w; ++j) wpre += wsum[j];
        int incl = s + wpre;
        int base = carry;
        if (i < n) { int ex = base + incl - v; row_ptr[i] = ex; cnt_cursor[i] = ex; }
        __syncthreads();
        if (t == 1023) carry = base + incl;
    }
    __syncthreads();
    if (t == 0) row_ptr[n] = carry;
}

__global__ void k_scatter(const int* __restrict__ src, const int* __restrict__ dst,
                          int* __restrict__ cursor, int* __restrict__ bucket, int E) {
    int e = blockIdx.x * 256 + threadIdx.x;
    if (e < E) {
        int p = atomicAdd(&cursor[dst[e]], 1);
        bucket[p] = src[e];
    }
}

// ---------------- conversions / weight repack ----------------

__global__ void k_convert_weights(const float* __restrict__ Wl1, const float* __restrict__ Wr1,
                                  const float* __restrict__ Wl2, const float* __restrict__ Wr2,
                                  const float* __restrict__ W1, const float* __restrict__ b1,
                                  unsigned short* __restrict__ Wc1,
                                  unsigned short* __restrict__ Wc2,
                                  unsigned short* __restrict__ W1g,
                                  unsigned short* __restrict__ WaF) {
    int idx = blockIdx.x * 256 + threadIdx.x;
    if (idx < 65536) {
        int c = idx >> 13, j = (idx >> 5) & 255, kk = idx & 31;
        float v = (c < 4) ? Wl1[j * 128 + c * 32 + kk] : Wr1[j * 128 + (c - 4) * 32 + kk];
        Wc1[idx] = f2b(v);
    } else if (idx < 65536 + 131072) {
        int i2 = idx - 65536;
        int c = i2 >> 13, j = (i2 >> 5) & 255, kk = i2 & 31;
        float v = (c < 8) ? Wl2[j * 256 + c * 32 + kk] : Wr2[j * 256 + (c - 8) * 32 + kk];
        Wc2[i2] = f2b(v);
    } else if (idx < 65536 + 131072 + 131072) {
        int i3 = idx - 65536 - 131072;
        int c = i3 >> 14, j = (i3 >> 5) & 511, kk = i3 & 31;
        float v = (j < 256) ? W1[(size_t)j * 528 + c * 32 + kk]
                            : W1[(size_t)(j - 256) * 528 + 256 + c * 32 + kk];
        W1g[i3] = f2b(v);
    } else if (idx < 65536 + 131072 + 131072 + 8192) {
        int i4 = idx - 65536 - 131072 - 131072;
        int mi = i4 >> 9, l = (i4 >> 3) & 63, j = i4 & 7;
        int m = mi * 16 + (l & 15);
        int k = (l >> 4) * 8 + j;
        float v = (k < 16) ? W1[(size_t)m * 528 + 512 + k] : (k == 16 ? b1[m] : 0.f);
        WaF[i4] = f2b(v);
    }
}

// x fp32 -> xb bf16 + xf8 e4m3
__global__ void k_xconvert(const float* __restrict__ in, unsigned short* __restrict__ xb,
                           unsigned char* __restrict__ xf8, int n) {
    int j = (blockIdx.x * 256 + threadIdx.x) * 2;
    if (j < n) {
        float a = in[j], b = in[j + 1];
        xb[j] = f2b(a); xb[j + 1] = f2b(b);
        unsigned p = __builtin_amdgcn_cvt_pk_fp8_f32(a, b, 0, false);
        *reinterpret_cast<unsigned short*>(xf8 + j) = (unsigned short)(p & 0xffffu);
    }
}

// ---------------- aggregation (mean over in-neighbors, fp8 gather) ----------------

__device__ __forceinline__ void accf8(uint2 v, float* s) {
    f32x2 p0 = __builtin_amdgcn_cvt_pk_f32_fp8(v.x, false);
    f32x2 p1 = __builtin_amdgcn_cvt_pk_f32_fp8(v.x, true);
    f32x2 p2 = __builtin_amdgcn_cvt_pk_f32_fp8(v.y, false);
    f32x2 p3 = __builtin_amdgcn_cvt_pk_f32_fp8(v.y, true);
    s[0] += p0.x; s[1] += p0.y; s[2] += p1.x; s[3] += p1.y;
    s[4] += p2.x; s[5] += p2.y; s[6] += p3.x; s[7] += p3.y;
}

__global__ __launch_bounds__(256) void k_agg_x(const unsigned char* __restrict__ xf8,
                                               const int* __restrict__ row_ptr,
                                               const int* __restrict__ bucket,
                                               unsigned short* __restrict__ agg, int Nn) {
    int node = blockIdx.x * 4 + (threadIdx.x >> 6);
    if (node >= Nn) return;
    int lane = threadIdx.x & 63;
    int q = lane >> 4, c = lane & 15;
    int beg = row_ptr[node], end = row_ptr[node + 1];
    int len = end - beg;
    int lo = beg + ((len * q) >> 2);
    int hi = beg + ((len * (q + 1)) >> 2);
    float s[8] = {0.f,0.f,0.f,0.f,0.f,0.f,0.f,0.f};
    const unsigned char* xp = xf8 + c * 8;
    int e = lo;
    for (; e + 4 <= hi; e += 4) {
        int b0 = bucket[e], b1 = bucket[e + 1], b2 = bucket[e + 2], b3 = bucket[e + 3];
        uint2 v0 = *reinterpret_cast<const uint2*>(xp + (size_t)b0 * 128);
        uint2 v1 = *reinterpret_cast<const uint2*>(xp + (size_t)b1 * 128);
        uint2 v2 = *reinterpret_cast<const uint2*>(xp + (size_t)b2 * 128);
        uint2 v3 = *reinterpret_cast<const uint2*>(xp + (size_t)b3 * 128);
        accf8(v0, s); accf8(v1, s); accf8(v2, s); accf8(v3, s);
    }
    for (; e < hi; ++e)
        accf8(*reinterpret_cast<const uint2*>(xp + (size_t)bucket[e] * 128), s);
    #pragma unroll
    for (int j = 0; j < 8; ++j) {
        s[j] += __shfl_xor(s[j], 16);
        s[j] += __shfl_xor(s[j], 32);
    }
    if (q == 0) {
        float sc = 1.0f / (float)(len > 1 ? len : 1);
        uint4 o;
        o.x = (unsigned)f2b(s[0]*sc) | ((unsigned)f2b(s[1]*sc) << 16);
        o.y = (unsigned)f2b(s[2]*sc) | ((unsigned)f2b(s[3]*sc) << 16);
        o.z = (unsigned)f2b(s[4]*sc) | ((unsigned)f2b(s[5]*sc) << 16);
        o.w = (unsigned)f2b(s[6]*sc) | ((unsigned)f2b(s[7]*sc) << 16);
        *reinterpret_cast<uint4*>(agg + (size_t)node * 128 + c * 8) = o;
    }
}

__global__ __launch_bounds__(256) void k_agg_h(const unsigned char* __restrict__ hf8,
                                               const int* __restrict__ row_ptr,
                                               const int* __restrict__ bucket,
                                               unsigned short* __restrict__ agg, int Nn) {
    int node = blockIdx.x * 4 + (threadIdx.x >> 6);
    if (node >= Nn) return;
    int lane = threadIdx.x & 63;
    int g = lane >> 5, c = lane & 31;
    int beg = row_ptr[node], end = row_ptr[node + 1];
    int len = end - beg;
    int lo = beg + ((len * g) >> 1);
    int hi = beg + ((len * (g + 1)) >> 1);
    float s[8] = {0.f,0.f,0.f,0.f,0.f,0.f,0.f,0.f};
    const unsigned char* hp = hf8 + c * 8;
    int e = lo;
    for (; e + 4 <= hi; e += 4) {
        int b0 = bucket[e], b1 = bucket[e + 1], b2 = bucket[e + 2], b3 = bucket[e + 3];
        uint2 v0 = *reinterpret_cast<const uint2*>(hp + (size_t)b0 * 256);
        uint2 v1 = *reinterpret_cast<const uint2*>(hp + (size_t)b1 * 256);
        uint2 v2 = *reinterpret_cast<const uint2*>(hp + (size_t)b2 * 256);
        uint2 v3 = *reinterpret_cast<const uint2*>(hp + (size_t)b3 * 256);
        accf8(v0, s); accf8(v1, s); accf8(v2, s); accf8(v3, s);
    }
    for (; e < hi; ++e)
        accf8(*reinterpret_cast<const uint2*>(hp + (size_t)bucket[e] * 256), s);
    #pragma unroll
    for (int j = 0; j < 8; ++j) s[j] += __shfl_xor(s[j], 32);
    if (g == 0) {
        float sc = 1.0f / (float)(len > 1 ? len : 1);
        uint4 o;
        o.x = (unsigned)f2b(s[0]*sc) | ((unsigned)f2b(s[1]*sc) << 16);
        o.y = (unsigned)f2b(s[2]*sc) | ((unsigned)f2b(s[3]*sc) << 16);
        o.z = (unsigned)f2b(s[4]*sc) | ((unsigned)f2b(s[5]*sc) << 16);
        o.w = (unsigned)f2b(s[6]*sc) | ((unsigned)f2b(s[7]*sc) << 16);
        *reinterpret_cast<uint4*>(agg + (size_t)node * 256 + c * 8) = o;
    }
}

// ---------------- conv GEMM: H = relu(bias + Aagg@Wl^T + Aself@Wr^T) ----------------

__global__ __launch_bounds__(256) void k_conv_gemm(const unsigned short* __restrict__ Aagg,
                                                   const unsigned short* __restrict__ Aself,
                                                   const unsigned short* __restrict__ Wck,
                                                   const float* __restrict__ bias,
                                                   unsigned short* __restrict__ Hout,
                                                   unsigned char* __restrict__ Hf8,
                                                   int Nn, int F) {
    __shared__ __align__(16) unsigned short zt[128 * 32];
    __shared__ __align__(16) unsigned short wt[128 * 32];
    const int t = threadIdx.x;
    const int lane = t & 63, w = t >> 6;
    const int wm = w >> 1, wn = w & 1;
    const int node0 = blockIdx.x * 128;
    const int colh = blockIdx.y;
    const int half = F >> 5, nchunks = F >> 4;

    f32x4 acc[4][4];
    #pragma unroll
    for (int i = 0; i < 4; ++i)
        #pragma unroll
        for (int j = 0; j < 4; ++j) acc[i][j] = (f32x4){0.f, 0.f, 0.f, 0.f};

    for (int c = 0; c < nchunks; ++c) {
        __syncthreads();
        const unsigned short* Asrc = (c < half) ? Aagg : Aself;
        const int ccol = ((c < half) ? c : c - half) * 32;
        #pragma unroll
        for (int p = 0; p < 2; ++p) {
            int fc = t + p * 256;
            int row = fc >> 2, seg = fc & 3;
            int node = node0 + row; if (node >= Nn) node = Nn - 1;
            uint4 v = *reinterpret_cast<const uint4*>(Asrc + (size_t)node * F + ccol + seg * 8);
            *reinterpret_cast<uint4*>(&zt[row * 32 + swz(row, seg) * 8]) = v;
        }
        const unsigned short* Wsrc = Wck + ((size_t)c * 256 + colh * 128) * 32;
        #pragma unroll
        for (int p = 0; p < 2; ++p) {
            int fc = t + p * 256;
            int row = fc >> 2, seg = fc & 3;
            *reinterpret_cast<uint4*>(&wt[row * 32 + swz(row, seg) * 8]) =
                *reinterpret_cast<const uint4*>(Wsrc + fc * 8);
        }
        __syncthreads();
        bf16x8 a[4], b[4];
        const int q = lane >> 4;
        #pragma unroll
        for (int mi = 0; mi < 4; ++mi) {
            int R = wm * 64 + mi * 16 + (lane & 15);
            a[mi] = *reinterpret_cast<const bf16x8*>(&zt[R * 32 + swz(R, q) * 8]);
        }
        #pragma unroll
        for (int ni = 0; ni < 4; ++ni) {
            int R = wn * 64 + ni * 16 + (lane & 15);
            b[ni] = *reinterpret_cast<const bf16x8*>(&wt[R * 32 + swz(R, q) * 8]);
        }
        #pragma unroll
        for (int mi = 0; mi < 4; ++mi)
            #pragma unroll
            for (int ni = 0; ni < 4; ++ni)
                acc[mi][ni] = __builtin_amdgcn_mfma_f32_16x16x32_bf16(a[mi], b[ni], acc[mi][ni], 0, 0, 0);
    }

    #pragma unroll
    for (int mi = 0; mi < 4; ++mi)
        #pragma unroll
        for (int ni = 0; ni < 4; ++ni) {
            int col = colh * 128 + wn * 64 + ni * 16 + (lane & 15);
            float bia = bias[col];
            #pragma unroll
            for (int r = 0; r < 4; ++r) {
                int row = node0 + wm * 64 + mi * 16 + ((lane >> 4) << 2) + r;
                if (row < Nn) {
                    float v = acc[mi][ni][r] + bia;
                    v = v > 0.f ? v : 0.f;
                    Hout[(size_t)row * 256 + col] = f2b(v);
                    if (Hf8) Hf8[(size_t)row * 256 + col] = f2f8(v);
                }
            }
        }
}

// ---------------- G GEMM: G2 = h2 @ [W1u;W1v]^T  ([N][512] bf16) ----------------

__global__ __launch_bounds__(256) void k_gemm_g(const unsigned short* __restrict__ A,
                                                const unsigned short* __restrict__ Wck,
                                                unsigned short* __restrict__ Gout,
                                                int Nn) {
    __shared__ __align__(16) unsigned short zt[128 * 32];
    __shared__ __align__(16) unsigned short wt[128 * 32];
    const int t = threadIdx.x;
    const int lane = t & 63, w = t >> 6;
    const int wm = w >> 1, wn = w & 1;
    const int node0 = blockIdx.x * 128;
    const int colg = blockIdx.y;

    f32x4 acc[4][4];
    #pragma unroll
    for (int i = 0; i < 4; ++i)
        #pragma unroll
        for (int j = 0; j < 4; ++j) acc[i][j] = (f32x4){0.f, 0.f, 0.f, 0.f};

    for (int c = 0; c < 8; ++c) {
        __syncthreads();
        #pragma unroll
        for (int p = 0; p < 2; ++p) {
            int fc = t + p * 256;
            int row = fc >> 2, seg = fc & 3;
            int node = node0 + row; if (node >= Nn) node = Nn - 1;
            uint4 v = *reinterpret_cast<const uint4*>(A + (size_t)node * 256 + c * 32 + seg * 8);
            *reinterpret_cast<uint4*>(&zt[row * 32 + swz(row, seg) * 8]) = v;
        }
        const unsigned short* Wsrc = Wck + ((size_t)c * 512 + colg * 128) * 32;
        #pragma unroll
        for (int p = 0; p < 2; ++p) {
            int fc = t + p * 256;
            int row = fc >> 2, seg = fc & 3;
            *reinterpret_cast<uint4*>(&wt[row * 32 + swz(row, seg) * 8]) =
                *reinterpret_cast<const uint4*>(Wsrc + fc * 8);
        }
        __syncthreads();
        bf16x8 a[4], b[4];
        const int q = lane >> 4;
        #pragma unroll
        for (int mi = 0; mi < 4; ++mi) {
            int R = wm * 64 + mi * 16 + (lane & 15);
            a[mi] = *reinterpret_cast<const bf16x8*>(&zt[R * 32 + swz(R, q) * 8]);
        }
        #pragma unroll
        for (int ni = 0; ni < 4; ++ni) {
            int R = wn * 64 + ni * 16 + (lane & 15);
            b[ni] = *reinterpret_cast<const bf16x8*>(&wt[R * 32 + swz(R, q) * 8]);
        }
        #pragma unroll
        for (int mi = 0; mi < 4; ++mi)
            #pragma unroll
            for (int ni = 0; ni < 4; ++ni)
                acc[mi][ni] = __builtin_amdgcn_mfma_f32_16x16x32_bf16(a[mi], b[ni], acc[mi][ni], 0, 0, 0);
    }

    #pragma unroll
    for (int mi = 0; mi < 4; ++mi)
        #pragma unroll
        for (int ni = 0; ni < 4; ++ni) {
            int col = colg * 128 + wn * 64 + ni * 16 + (lane & 15);
            #pragma unroll
            for (int r = 0; r < 4; ++r) {
                int row = node0 + wm * 64 + mi * 16 + ((lane >> 4) << 2) + r;
                if (row < Nn)
                    Gout[(size_t)row * 512 + col] = f2b(acc[mi][ni][r]);
            }
        }
}

// ---------------- edge kernel v4 ----------------
// Two half-feature passes; per pass: phase A stages summed g (cheap trunc add,
// 4 edges per load instr, 256B contiguous per edge) into per-wave LDS rows,
// phase B runs 8 MFMAs + relu·W2 partial. 23.5 KB LDS -> 6 blocks/CU.

__global__ __launch_bounds__(256, 6) void k_edge(const unsigned short* __restrict__ G2,
                                                 const float* __restrict__ attr,
                                                 const int* __restrict__ eu,
                                                 const int* __restrict__ ev,
                                                 const uint4* __restrict__ WaF,
                                                 const float* __restrict__ W2,
                                                 const float* __restrict__ b2,
                                                 const float* __restrict__ logexp,
                                                 float* __restrict__ out, int P) {
    __shared__ __align__(16) unsigned short attrT[64 * 40];
    __shared__ __align__(16) unsigned short gt[64 * 132];   // per-wave rows, 128 cols + pad
    __shared__ float w2s[256];
    __shared__ int euv[128];                                // [2e]=u, [2e+1]=v
    const int t = threadIdx.x;
    const int lane = t & 63, w = t >> 6;
    const int base = blockIdx.x * 64;

    // stage attr -> attrT (cols 0..15 attr, 16 = 1.0 (b1 row), 17..31 = 0)
    {
        int e = t >> 2, seg = t & 3;
        int eg = base + e; if (eg >= P) eg = P - 1;
        const float4 f = *reinterpret_cast<const float4*>(attr + (size_t)eg * 16 + seg * 4);
        uint2 o;
        o.x = (unsigned)f2b(f.x) | ((unsigned)f2b(f.y) << 16);
        o.y = (unsigned)f2b(f.z) | ((unsigned)f2b(f.w) << 16);
        *reinterpret_cast<uint2*>(&attrT[e * 40 + seg * 4]) = o;
    }
    if (t < 64) {
        uint2 z0; z0.x = 0x3f80u; z0.y = 0u;
        *reinterpret_cast<uint2*>(&attrT[t * 40 + 16]) = z0;
        uint2 z1; z1.x = 0u; z1.y = 0u;
        *reinterpret_cast<uint2*>(&attrT[t * 40 + 20]) = z1;
        uint4 z2; z2.x = z2.y = z2.z = z2.w = 0u;
        *reinterpret_cast<uint4*>(&attrT[t * 40 + 24]) = z2;
    }
    if (t < 128) {
        int e = t >> 1;
        int eg = base + e; if (eg >= P) eg = P - 1;
        euv[t] = (t & 1) ? ev[eg] : eu[eg];
    }
    w2s[t] = W2[t];
    __syncthreads();

    const int el = lane & 15, q = lane >> 4;
    const int grow = w * 16 + el;
    const bf16x8 bfrag = *reinterpret_cast<const bf16x8*>(&attrT[grow * 40 + q * 8]);

    float s = 0.f;
    #pragma unroll
    for (int p = 0; p < 2; ++p) {
        // phase A: stage cols [p*128, p*128+128) of g = Gu + Gv, 4 edges/instr
        {
            const int sub = lane >> 4, c = lane & 15;
            #pragma unroll
            for (int i = 0; i < 4; ++i) {
                int le = w * 16 + i * 4 + sub;
                int u = euv[2 * le], v = euv[2 * le + 1];
                uint4 a = *reinterpret_cast<const uint4*>(G2 + (size_t)u * 512 + p * 128 + c * 8);
                uint4 b = *reinterpret_cast<const uint4*>(G2 + (size_t)v * 512 + 256 + p * 128 + c * 8);
                uint4 o;
                o.x = padd(a.x, b.x);
                o.y = padd(a.y, b.y);
                o.z = padd(a.z, b.z);
                o.w = padd(a.w, b.w);
                *reinterpret_cast<uint4*>(&gt[le * 132 + c * 8]) = o;
            }
        }
        // phase B: 8 MFMAs over this feature half (wave reads only rows it wrote)
        #pragma unroll
        for (int m = 0; m < 8; ++m) {
            const int mi = p * 8 + m;
            const bf16x8 af = *reinterpret_cast<const bf16x8*>(&WaF[mi * 64 + lane]);
            f32x4 acc = __builtin_amdgcn_mfma_f32_16x16x32_bf16(af, bfrag, (f32x4){0.f,0.f,0.f,0.f}, 0, 0, 0);
            const uint2 g2v = *reinterpret_cast<const uint2*>(&gt[grow * 132 + m * 16 + q * 4]);
            const float4 w2v = *reinterpret_cast<const float4*>(&w2s[mi * 16 + q * 4]);
            float y0 = acc[0] + blo(g2v.x);
            float y1 = acc[1] + bhi(g2v.x);
            float y2 = acc[2] + blo(g2v.y);
            float y3 = acc[3] + bhi(g2v.y);
            s += (y0 > 0.f ? y0 : 0.f) * w2v.x;
            s += (y1 > 0.f ? y1 : 0.f) * w2v.y;
            s += (y2 > 0.f ? y2 : 0.f) * w2v.z;
            s += (y3 > 0.f ? y3 : 0.f) * w2v.w;
        }
        if (p == 0) __syncthreads();   // pass-1 writes reuse gt rows: drain pass-0 reads
    }
    s += __shfl_xor(s, 16);
    s += __shfl_xor(s, 32);
    int eg = base + grow;
    if (q == 0 && eg < P)
        out[eg] = logexp[eg] + b2[0] + s;
}

// ---------------- launch ----------------

extern "C" void kernel_launch(void* const* d_in, const int* in_sizes, int n_in,
                              void* d_out, int out_size, void* d_ws, size_t ws_size,
                              hipStream_t stream) {
    const float* x      = (const float*)d_in[0];
    const int*   eidx   = (const int*)d_in[1];
    const int*   eu     = (const int*)d_in[2];
    const int*   ev     = (const int*)d_in[3];
    const float* attr   = (const float*)d_in[4];
    const float* logexp = (const float*)d_in[5];
    const float* Wl1    = (const float*)d_in[6];
    const float* bl1    = (const float*)d_in[7];
    const float* Wr1    = (const float*)d_in[8];
    const float* Wl2    = (const float*)d_in[9];
    const float* bl2    = (const float*)d_in[10];
    const float* Wr2    = (const float*)d_in[11];
    const float* W1     = (const float*)d_in[12];
    const float* b1     = (const float*)d_in[13];
    const float* W2     = (const float*)d_in[14];
    const float* b2     = (const float*)d_in[15];
    float* out = (float*)d_out;

    const int N = in_sizes[0] / 128;
    const int E = in_sizes[1] / 2;
    const int P = in_sizes[2];
    const int* src = eidx;
    const int* dst = eidx + E;

    char* ws = (char*)d_ws;
    size_t off = 0;
    auto alloc = [&](size_t bytes) -> void* {
        off = (off + 255) & ~(size_t)255;
        void* p = ws + off;
        off += bytes;
        return p;
    };
    int* row_ptr = (int*)alloc((size_t)(N + 1) * 4);
    int* cursor  = (int*)alloc((size_t)N * 4);
    int* bucket  = (int*)alloc((size_t)E * 4);
    unsigned short* h1 = (unsigned short*)alloc((size_t)N * 256 * 2);
    unsigned short* h2 = (unsigned short*)alloc((size_t)N * 256 * 2);
    char* shared_base = (char*)alloc((size_t)N * 512 * 2);
    unsigned short* xb   = (unsigned short*)shared_base;                         // N*128
    unsigned short* agg1 = (unsigned short*)(shared_base + (size_t)N * 128 * 2); // N*128
    unsigned short* agg2 = (unsigned short*)(shared_base + (size_t)N * 256 * 2); // N*256
    unsigned short* G2   = (unsigned short*)shared_base;                         // N*512
    unsigned char* xf8  = (unsigned char*)alloc((size_t)N * 128);
    unsigned char* h1f8 = (unsigned char*)alloc((size_t)N * 256);
    unsigned short* Wc1  = (unsigned short*)alloc((size_t)65536 * 2);
    unsigned short* Wc2  = (unsigned short*)alloc((size_t)131072 * 2);
    unsigned short* W1g  = (unsigned short*)alloc((size_t)131072 * 2);
    unsigned short* WaF  = (unsigned short*)alloc((size_t)8192 * 2);

    hipMemsetAsync(cursor, 0, (size_t)N * 4, stream);
    k_count<<<(E + 255) / 256, 256, 0, stream>>>(dst, cursor, E);
    k_scan<<<1, 1024, 0, stream>>>(cursor, row_ptr, N);
    k_scatter<<<(E + 255) / 256, 256, 0, stream>>>(src, dst, cursor, bucket, E);
    k_convert_weights<<<(65536 + 131072 + 131072 + 8192 + 255) / 256, 256, 0, stream>>>(
        Wl1, Wr1, Wl2, Wr2, W1, b1, Wc1, Wc2, W1g, WaF);
    k_xconvert<<<(N * 64 + 255) / 256, 256, 0, stream>>>(x, xb, xf8, N * 128);

    k_agg_x<<<(N + 3) / 4, 256, 0, stream>>>(xf8, row_ptr, bucket, agg1, N);
    dim3 gconv((N + 127) / 128, 2);
    k_conv_gemm<<<gconv, 256, 0, stream>>>(agg1, xb, Wc1, bl1, h1, h1f8, N, 128);
    k_agg_h<<<(N + 3) / 4, 256, 0, stream>>>(h1f8, row_ptr, bucket, agg2, N);
    k_conv_gemm<<<gconv, 256, 0, stream>>>(agg2, h1, Wc2, bl2, h2, (unsigned char*)nullptr, N, 256);

    dim3 gg((N + 127) / 128, 4);
    k_gemm_g<<<gg, 256, 0, stream>>>(h2, W1g, G2, N);
    k_edge<<<(P + 63) / 64, 256, 0, stream>>>(G2, attr, eu, ev, (const uint4*)WaF,
                                              W2, b2, logexp, out, P);
}

// Round 8
// 479.563 us; speedup vs baseline: 1.1145x; 1.0496x over previous
//
#include <hip/hip_runtime.h>

// GraphSAGE_13993003450942 — round 8:
//  - G2 stored fp8 e4m3: k_edge gather bytes halve (253->128 MB); raw fp8 LDS
//    staging (zero VALU phase A), cvt_pk_f32_fp8 unpack in phase B.
//  - k_scan: wave-0 parallel scan of wave-sums (was 15 dependent LDS reads/chunk).

typedef float f32x4 __attribute__((ext_vector_type(4)));
typedef float f32x2 __attribute__((ext_vector_type(2)));
typedef __bf16 bf16x8 __attribute__((ext_vector_type(8)));

__device__ __forceinline__ unsigned short f2b(float f) {
    unsigned u = __float_as_uint(f);
    u = u + 0x7fffu + ((u >> 16) & 1u);   // RNE
    return (unsigned short)(u >> 16);
}
__device__ __forceinline__ float b2f(unsigned short s) {
    return __uint_as_float(((unsigned)s) << 16);
}
__device__ __forceinline__ int swz(int r, int g) { return (g + (r >> 1)) & 3; }
__device__ __forceinline__ unsigned char f2f8(float v) {
    return (unsigned char)(__builtin_amdgcn_cvt_pk_fp8_f32(v, v, 0, false) & 0xff);
}

// ---------------- CSR build ----------------

__global__ void k_count(const int* __restrict__ dst, int* __restrict__ cnt, int E) {
    int e = blockIdx.x * 256 + threadIdx.x;
    if (e < E) atomicAdd(&cnt[dst[e]], 1);
}

__global__ __launch_bounds__(1024) void k_scan(int* __restrict__ cnt_cursor,
                                               int* __restrict__ row_ptr, int n) {
    __shared__ int wsum[16];
    __shared__ int carry, wtot;
    int t = threadIdx.x, lane = t & 63, w = t >> 6;
    if (t == 0) carry = 0;
    __syncthreads();
    int nch = (n + 1023) >> 10;
    for (int ch = 0; ch < nch; ++ch) {
        int i = (ch << 10) + t;
        int v = (i < n) ? cnt_cursor[i] : 0;
        int s = v;
        #pragma unroll
        for (int off = 1; off < 64; off <<= 1) {
            int u = __shfl_up(s, off);
            if (lane >= off) s += u;
        }
        if (lane == 63) wsum[w] = s;
        __syncthreads();
        if (t < 16) {
            int vv = wsum[t];
            int s2 = vv;
            #pragma unroll
            for (int off = 1; off < 16; off <<= 1) {
                int u = __shfl_up(s2, off);
                if (t >= off) s2 += u;
            }
            wsum[t] = s2 - vv;            // exclusive prefix of wave-sums
            if (t == 15) wtot = s2;
        }
        __syncthreads();
        int base = carry;
        int incl = s + wsum[w];
        if (i < n) { int ex = base + incl - v; row_ptr[i] = ex; cnt_cursor[i] = ex; }
        __syncthreads();
        if (t == 0) carry = base + wtot;
    }
    __syncthreads();
    if (t == 0) row_ptr[n] = carry;
}

__global__ void k_scatter(const int* __restrict__ src, const int* __restrict__ dst,
                          int* __restrict__ cursor, int* __restrict__ bucket, int E) {
    int e = blockIdx.x * 256 + threadIdx.x;
    if (e < E) {
        int p = atomicAdd(&cursor[dst[e]], 1);
        bucket[p] = src[e];
    }
}

// ---------------- conversions / weight repack ----------------

__global__ void k_convert_weights(const float* __restrict__ Wl1, const float* __restrict__ Wr1,
                                  const float* __restrict__ Wl2, const float* __restrict__ Wr2,
                                  const float* __restrict__ W1, const float* __restrict__ b1,
                                  unsigned short* __restrict__ Wc1,
                                  unsigned short* __restrict__ Wc2,
                                  unsigned short* __restrict__ W1g,
                                  unsigned short* __restrict__ WaF) {
    int idx = blockIdx.x * 256 + threadIdx.x;
    if (idx < 65536) {
        int c = idx >> 13, j = (idx >> 5) & 255, kk = idx & 31;
        float v = (c < 4) ? Wl1[j * 128 + c * 32 + kk] : Wr1[j * 128 + (c - 4) * 32 + kk];
        Wc1[idx] = f2b(v);
    } else if (idx < 65536 + 131072) {
        int i2 = idx - 65536;
        int c = i2 >> 13, j = (i2 >> 5) & 255, kk = i2 & 31;
        float v = (c < 8) ? Wl2[j * 256 + c * 32 + kk] : Wr2[j * 256 + (c - 8) * 32 + kk];
        Wc2[i2] = f2b(v);
    } else if (idx < 65536 + 131072 + 131072) {
        int i3 = idx - 65536 - 131072;
        int c = i3 >> 14, j = (i3 >> 5) & 511, kk = i3 & 31;
        float v = (j < 256) ? W1[(size_t)j * 528 + c * 32 + kk]
                            : W1[(size_t)(j - 256) * 528 + 256 + c * 32 + kk];
        W1g[i3] = f2b(v);
    } else if (idx < 65536 + 131072 + 131072 + 8192) {
        int i4 = idx - 65536 - 131072 - 131072;
        int mi = i4 >> 9, l = (i4 >> 3) & 63, j = i4 & 7;
        int m = mi * 16 + (l & 15);
        int k = (l >> 4) * 8 + j;
        float v = (k < 16) ? W1[(size_t)m * 528 + 512 + k] : (k == 16 ? b1[m] : 0.f);
        WaF[i4] = f2b(v);
    }
}

// x fp32 -> xb bf16 + xf8 e4m3
__global__ void k_xconvert(const float* __restrict__ in, unsigned short* __restrict__ xb,
                           unsigned char* __restrict__ xf8, int n) {
    int j = (blockIdx.x * 256 + threadIdx.x) * 2;
    if (j < n) {
        float a = in[j], b = in[j + 1];
        xb[j] = f2b(a); xb[j + 1] = f2b(b);
        unsigned p = __builtin_amdgcn_cvt_pk_fp8_f32(a, b, 0, false);
        *reinterpret_cast<unsigned short*>(xf8 + j) = (unsigned short)(p & 0xffffu);
    }
}

// ---------------- aggregation (mean over in-neighbors, fp8 gather) ----------------

__device__ __forceinline__ void accf8(uint2 v, float* s) {
    f32x2 p0 = __builtin_amdgcn_cvt_pk_f32_fp8(v.x, false);
    f32x2 p1 = __builtin_amdgcn_cvt_pk_f32_fp8(v.x, true);
    f32x2 p2 = __builtin_amdgcn_cvt_pk_f32_fp8(v.y, false);
    f32x2 p3 = __builtin_amdgcn_cvt_pk_f32_fp8(v.y, true);
    s[0] += p0.x; s[1] += p0.y; s[2] += p1.x; s[3] += p1.y;
    s[4] += p2.x; s[5] += p2.y; s[6] += p3.x; s[7] += p3.y;
}

__global__ __launch_bounds__(256) void k_agg_x(const unsigned char* __restrict__ xf8,
                                               const int* __restrict__ row_ptr,
                                               const int* __restrict__ bucket,
                                               unsigned short* __restrict__ agg, int Nn) {
    int node = blockIdx.x * 4 + (threadIdx.x >> 6);
    if (node >= Nn) return;
    int lane = threadIdx.x & 63;
    int q = lane >> 4, c = lane & 15;
    int beg = row_ptr[node], end = row_ptr[node + 1];
    int len = end - beg;
    int lo = beg + ((len * q) >> 2);
    int hi = beg + ((len * (q + 1)) >> 2);
    float s[8] = {0.f,0.f,0.f,0.f,0.f,0.f,0.f,0.f};
    const unsigned char* xp = xf8 + c * 8;
    int e = lo;
    for (; e + 4 <= hi; e += 4) {
        int b0 = bucket[e], b1 = bucket[e + 1], b2 = bucket[e + 2], b3 = bucket[e + 3];
        uint2 v0 = *reinterpret_cast<const uint2*>(xp + (size_t)b0 * 128);
        uint2 v1 = *reinterpret_cast<const uint2*>(xp + (size_t)b1 * 128);
        uint2 v2 = *reinterpret_cast<const uint2*>(xp + (size_t)b2 * 128);
        uint2 v3 = *reinterpret_cast<const uint2*>(xp + (size_t)b3 * 128);
        accf8(v0, s); accf8(v1, s); accf8(v2, s); accf8(v3, s);
    }
    for (; e < hi; ++e)
        accf8(*reinterpret_cast<const uint2*>(xp + (size_t)bucket[e] * 128), s);
    #pragma unroll
    for (int j = 0; j < 8; ++j) {
        s[j] += __shfl_xor(s[j], 16);
        s[j] += __shfl_xor(s[j], 32);
    }
    if (q == 0) {
        float sc = 1.0f / (float)(len > 1 ? len : 1);
        uint4 o;
        o.x = (unsigned)f2b(s[0]*sc) | ((unsigned)f2b(s[1]*sc) << 16);
        o.y = (unsigned)f2b(s[2]*sc) | ((unsigned)f2b(s[3]*sc) << 16);
        o.z = (unsigned)f2b(s[4]*sc) | ((unsigned)f2b(s[5]*sc) << 16);
        o.w = (unsigned)f2b(s[6]*sc) | ((unsigned)f2b(s[7]*sc) << 16);
        *reinterpret_cast<uint4*>(agg + (size_t)node * 128 + c * 8) = o;
    }
}

__global__ __launch_bounds__(256) void k_agg_h(const unsigned char* __restrict__ hf8,
                                               const int* __restrict__ row_ptr,
                                               const int* __restrict__ bucket,
                                               unsigned short* __restrict__ agg, int Nn) {
    int node = blockIdx.x * 4 + (threadIdx.x >> 6);
    if (node >= Nn) return;
    int lane = threadIdx.x & 63;
    int g = lane >> 5, c = lane & 31;
    int beg = row_ptr[node], end = row_ptr[node + 1];
    int len = end - beg;
    int lo = beg + ((len * g) >> 1);
    int hi = beg + ((len * (g + 1)) >> 1);
    float s[8] = {0.f,0.f,0.f,0.f,0.f,0.f,0.f,0.f};
    const unsigned char* hp = hf8 + c * 8;
    int e = lo;
    for (; e + 4 <= hi; e += 4) {
        int b0 = bucket[e], b1 = bucket[e + 1], b2 = bucket[e + 2], b3 = bucket[e + 3];
        uint2 v0 = *reinterpret_cast<const uint2*>(hp + (size_t)b0 * 256);
        uint2 v1 = *reinterpret_cast<const uint2*>(hp + (size_t)b1 * 256);
        uint2 v2 = *reinterpret_cast<const uint2*>(hp + (size_t)b2 * 256);
        uint2 v3 = *reinterpret_cast<const uint2*>(hp + (size_t)b3 * 256);
        accf8(v0, s); accf8(v1, s); accf8(v2, s); accf8(v3, s);
    }
    for (; e < hi; ++e)
        accf8(*reinterpret_cast<const uint2*>(hp + (size_t)bucket[e] * 256), s);
    #pragma unroll
    for (int j = 0; j < 8; ++j) s[j] += __shfl_xor(s[j], 32);
    if (g == 0) {
        float sc = 1.0f / (float)(len > 1 ? len : 1);
        uint4 o;
        o.x = (unsigned)f2b(s[0]*sc) | ((unsigned)f2b(s[1]*sc) << 16);
        o.y = (unsigned)f2b(s[2]*sc) | ((unsigned)f2b(s[3]*sc) << 16);
        o.z = (unsigned)f2b(s[4]*sc) | ((unsigned)f2b(s[5]*sc) << 16);
        o.w = (unsigned)f2b(s[6]*sc) | ((unsigned)f2b(s[7]*sc) << 16);
        *reinterpret_cast<uint4*>(agg + (size_t)node * 256 + c * 8) = o;
    }
}

// ---------------- conv GEMM: H = relu(bias + Aagg@Wl^T + Aself@Wr^T) ----------------

__global__ __launch_bounds__(256) void k_conv_gemm(const unsigned short* __restrict__ Aagg,
                                                   const unsigned short* __restrict__ Aself,
                                                   const unsigned short* __restrict__ Wck,
                                                   const float* __restrict__ bias,
                                                   unsigned short* __restrict__ Hout,
                                                   unsigned char* __restrict__ Hf8,
                                                   int Nn, int F) {
    __shared__ __align__(16) unsigned short zt[128 * 32];
    __shared__ __align__(16) unsigned short wt[128 * 32];
    const int t = threadIdx.x;
    const int lane = t & 63, w = t >> 6;
    const int wm = w >> 1, wn = w & 1;
    const int node0 = blockIdx.x * 128;
    const int colh = blockIdx.y;
    const int half = F >> 5, nchunks = F >> 4;

    f32x4 acc[4][4];
    #pragma unroll
    for (int i = 0; i < 4; ++i)
        #pragma unroll
        for (int j = 0; j < 4; ++j) acc[i][j] = (f32x4){0.f, 0.f, 0.f, 0.f};

    for (int c = 0; c < nchunks; ++c) {
        __syncthreads();
        const unsigned short* Asrc = (c < half) ? Aagg : Aself;
        const int ccol = ((c < half) ? c : c - half) * 32;
        #pragma unroll
        for (int p = 0; p < 2; ++p) {
            int fc = t + p * 256;
            int row = fc >> 2, seg = fc & 3;
            int node = node0 + row; if (node >= Nn) node = Nn - 1;
            uint4 v = *reinterpret_cast<const uint4*>(Asrc + (size_t)node * F + ccol + seg * 8);
            *reinterpret_cast<uint4*>(&zt[row * 32 + swz(row, seg) * 8]) = v;
        }
        const unsigned short* Wsrc = Wck + ((size_t)c * 256 + colh * 128) * 32;
        #pragma unroll
        for (int p = 0; p < 2; ++p) {
            int fc = t + p * 256;
            int row = fc >> 2, seg = fc & 3;
            *reinterpret_cast<uint4*>(&wt[row * 32 + swz(row, seg) * 8]) =
                *reinterpret_cast<const uint4*>(Wsrc + fc * 8);
        }
        __syncthreads();
        bf16x8 a[4], b[4];
        const int q = lane >> 4;
        #pragma unroll
        for (int mi = 0; mi < 4; ++mi) {
            int R = wm * 64 + mi * 16 + (lane & 15);
            a[mi] = *reinterpret_cast<const bf16x8*>(&zt[R * 32 + swz(R, q) * 8]);
        }
        #pragma unroll
        for (int ni = 0; ni < 4; ++ni) {
            int R = wn * 64 + ni * 16 + (lane & 15);
            b[ni] = *reinterpret_cast<const bf16x8*>(&wt[R * 32 + swz(R, q) * 8]);
        }
        #pragma unroll
        for (int mi = 0; mi < 4; ++mi)
            #pragma unroll
            for (int ni = 0; ni < 4; ++ni)
                acc[mi][ni] = __builtin_amdgcn_mfma_f32_16x16x32_bf16(a[mi], b[ni], acc[mi][ni], 0, 0, 0);
    }

    #pragma unroll
    for (int mi = 0; mi < 4; ++mi)
        #pragma unroll
        for (int ni = 0; ni < 4; ++ni) {
            int col = colh * 128 + wn * 64 + ni * 16 + (lane & 15);
            float bia = bias[col];
            #pragma unroll
            for (int r = 0; r < 4; ++r) {
                int row = node0 + wm * 64 + mi * 16 + ((lane >> 4) << 2) + r;
                if (row < Nn) {
                    float v = acc[mi][ni][r] + bia;
                    v = v > 0.f ? v : 0.f;
                    Hout[(size_t)row * 256 + col] = f2b(v);
                    if (Hf8) Hf8[(size_t)row * 256 + col] = f2f8(v);
                }
            }
        }
}

// ---------------- G GEMM: G2f8 = fp8(h2 @ [W1u;W1v]^T)  ([N][512] bytes) ----------------

__global__ __launch_bounds__(256) void k_gemm_g(const unsigned short* __restrict__ A,
                                                const unsigned short* __restrict__ Wck,
                                                unsigned char* __restrict__ Gout,
                                                int Nn) {
    __shared__ __align__(16) unsigned short zt[128 * 32];
    __shared__ __align__(16) unsigned short wt[128 * 32];
    const int t = threadIdx.x;
    const int lane = t & 63, w = t >> 6;
    const int wm = w >> 1, wn = w & 1;
    const int node0 = blockIdx.x * 128;
    const int colg = blockIdx.y;

    f32x4 acc[4][4];
    #pragma unroll
    for (int i = 0; i < 4; ++i)
        #pragma unroll
        for (int j = 0; j < 4; ++j) acc[i][j] = (f32x4){0.f, 0.f, 0.f, 0.f};

    for (int c = 0; c < 8; ++c) {
        __syncthreads();
        #pragma unroll
        for (int p = 0; p < 2; ++p) {
            int fc = t + p * 256;
            int row = fc >> 2, seg = fc & 3;
            int node = node0 + row; if (node >= Nn) node = Nn - 1;
            uint4 v = *reinterpret_cast<const uint4*>(A + (size_t)node * 256 + c * 32 + seg * 8);
            *reinterpret_cast<uint4*>(&zt[row * 32 + swz(row, seg) * 8]) = v;
        }
        const unsigned short* Wsrc = Wck + ((size_t)c * 512 + colg * 128) * 32;
        #pragma unroll
        for (int p = 0; p < 2; ++p) {
            int fc = t + p * 256;
            int row = fc >> 2, seg = fc & 3;
            *reinterpret_cast<uint4*>(&wt[row * 32 + swz(row, seg) * 8]) =
                *reinterpret_cast<const uint4*>(Wsrc + fc * 8);
        }
        __syncthreads();
        bf16x8 a[4], b[4];
        const int q = lane >> 4;
        #pragma unroll
        for (int mi = 0; mi < 4; ++mi) {
            int R = wm * 64 + mi * 16 + (lane & 15);
            a[mi] = *reinterpret_cast<const bf16x8*>(&zt[R * 32 + swz(R, q) * 8]);
        }
        #pragma unroll
        for (int ni = 0; ni < 4; ++ni) {
            int R = wn * 64 + ni * 16 + (lane & 15);
            b[ni] = *reinterpret_cast<const bf16x8*>(&wt[R * 32 + swz(R, q) * 8]);
        }
        #pragma unroll
        for (int mi = 0; mi < 4; ++mi)
            #pragma unroll
            for (int ni = 0; ni < 4; ++ni)
                acc[mi][ni] = __builtin_amdgcn_mfma_f32_16x16x32_bf16(a[mi], b[ni], acc[mi][ni], 0, 0, 0);
    }

    #pragma unroll
    for (int mi = 0; mi < 4; ++mi)
        #pragma unroll
        for (int ni = 0; ni < 4; ++ni) {
            int col = colg * 128 + wn * 64 + ni * 16 + (lane & 15);
            #pragma unroll
            for (int r = 0; r < 4; ++r) {
                int row = node0 + wm * 64 + mi * 16 + ((lane >> 4) << 2) + r;
                if (row < Nn)
                    Gout[(size_t)row * 512 + col] = f2f8(acc[mi][ni][r]);
            }
        }
}

// ---------------- edge kernel v5 (fp8 G2) ----------------
// Two half-feature passes; phase A: raw fp8 copy (4 edges/instr, 128B/edge/pass
// each for Gu and Gv), phase B: MFMA attr-term + fp8 unpack + relu·W2 reduce.

__global__ __launch_bounds__(256, 6) void k_edge(const unsigned char* __restrict__ G2,
                                                 const float* __restrict__ attr,
                                                 const int* __restrict__ eu,
                                                 const int* __restrict__ ev,
                                                 const uint4* __restrict__ WaF,
                                                 const float* __restrict__ W2,
                                                 const float* __restrict__ b2,
                                                 const float* __restrict__ logexp,
                                                 float* __restrict__ out, int P) {
    __shared__ __align__(16) unsigned short attrT[64 * 40];
    __shared__ __align__(16) unsigned char gt[64 * 264];  // per edge: 0-127 gu, 128-255 gv, pad 8
    __shared__ float w2s[256];
    __shared__ int euv[128];
    const int t = threadIdx.x;
    const int lane = t & 63, w = t >> 6;
    const int base = blockIdx.x * 64;

    {
        int e = t >> 2, seg = t & 3;
        int eg = base + e; if (eg >= P) eg = P - 1;
        const float4 f = *reinterpret_cast<const float4*>(attr + (size_t)eg * 16 + seg * 4);
        uint2 o;
        o.x = (unsigned)f2b(f.x) | ((unsigned)f2b(f.y) << 16);
        o.y = (unsigned)f2b(f.z) | ((unsigned)f2b(f.w) << 16);
        *reinterpret_cast<uint2*>(&attrT[e * 40 + seg * 4]) = o;
    }
    if (t < 64) {
        uint2 z0; z0.x = 0x3f80u; z0.y = 0u;
        *reinterpret_cast<uint2*>(&attrT[t * 40 + 16]) = z0;
        uint2 z1; z1.x = 0u; z1.y = 0u;
        *reinterpret_cast<uint2*>(&attrT[t * 40 + 20]) = z1;
        uint4 z2; z2.x = z2.y = z2.z = z2.w = 0u;
        *reinterpret_cast<uint4*>(&attrT[t * 40 + 24]) = z2;
    }
    if (t < 128) {
        int e = t >> 1;
        int eg = base + e; if (eg >= P) eg = P - 1;
        euv[t] = (t & 1) ? ev[eg] : eu[eg];
    }
    w2s[t] = W2[t];
    __syncthreads();

    const int el = lane & 15, q = lane >> 4;
    const int grow = w * 16 + el;
    const bf16x8 bfrag = *reinterpret_cast<const bf16x8*>(&attrT[grow * 40 + q * 8]);

    float s = 0.f;
    #pragma unroll
    for (int p = 0; p < 2; ++p) {
        // phase A: copy fp8 bytes [p*128, p*128+128) of Gu and Gv, 4 edges/instr
        {
            const int sub = lane >> 4, c = lane & 15;
            #pragma unroll
            for (int i = 0; i < 4; ++i) {
                int le = w * 16 + i * 4 + sub;
                int u = euv[2 * le], v = euv[2 * le + 1];
                uint2 a = *reinterpret_cast<const uint2*>(G2 + (size_t)u * 512 + p * 128 + c * 8);
                uint2 b = *reinterpret_cast<const uint2*>(G2 + (size_t)v * 512 + 256 + p * 128 + c * 8);
                *reinterpret_cast<uint2*>(&gt[le * 264 + c * 8]) = a;
                *reinterpret_cast<uint2*>(&gt[le * 264 + 128 + c * 8]) = b;
            }
        }
        // phase B: 8 MFMAs over this feature half (wave reads only rows it wrote)
        #pragma unroll
        for (int m = 0; m < 8; ++m) {
            const int mi = p * 8 + m;
            const bf16x8 af = *reinterpret_cast<const bf16x8*>(&WaF[mi * 64 + lane]);
            f32x4 acc = __builtin_amdgcn_mfma_f32_16x16x32_bf16(af, bfrag, (f32x4){0.f,0.f,0.f,0.f}, 0, 0, 0);
            const unsigned gu4 = *reinterpret_cast<const unsigned*>(&gt[grow * 264 + m * 16 + q * 4]);
            const unsigned gv4 = *reinterpret_cast<const unsigned*>(&gt[grow * 264 + 128 + m * 16 + q * 4]);
            const float4 w2v = *reinterpret_cast<const float4*>(&w2s[mi * 16 + q * 4]);
            f32x2 ulo = __builtin_amdgcn_cvt_pk_f32_fp8(gu4, false);
            f32x2 uhi = __builtin_amdgcn_cvt_pk_f32_fp8(gu4, true);
            f32x2 vlo = __builtin_amdgcn_cvt_pk_f32_fp8(gv4, false);
            f32x2 vhi = __builtin_amdgcn_cvt_pk_f32_fp8(gv4, true);
            float y0 = acc[0] + ulo.x + vlo.x;
            float y1 = acc[1] + ulo.y + vlo.y;
            float y2 = acc[2] + uhi.x + vhi.x;
            float y3 = acc[3] + uhi.y + vhi.y;
            s += (y0 > 0.f ? y0 : 0.f) * w2v.x;
            s += (y1 > 0.f ? y1 : 0.f) * w2v.y;
            s += (y2 > 0.f ? y2 : 0.f) * w2v.z;
            s += (y3 > 0.f ? y3 : 0.f) * w2v.w;
        }
        if (p == 0) __syncthreads();   // pass-1 writes reuse gt rows: drain pass-0 reads
    }
    s += __shfl_xor(s, 16);
    s += __shfl_xor(s, 32);
    int eg = base + grow;
    if (q == 0 && eg < P)
        out[eg] = logexp[eg] + b2[0] + s;
}

// ---------------- launch ----------------

extern "C" void kernel_launch(void* const* d_in, const int* in_sizes, int n_in,
                              void* d_out, int out_size, void* d_ws, size_t ws_size,
                              hipStream_t stream) {
    const float* x      = (const float*)d_in[0];
    const int*   eidx   = (const int*)d_in[1];
    const int*   eu     = (const int*)d_in[2];
    const int*   ev     = (const int*)d_in[3];
    const float* attr   = (const float*)d_in[4];
    const float* logexp = (const float*)d_in[5];
    const float* Wl1    = (const float*)d_in[6];
    const float* bl1    = (const float*)d_in[7];
    const float* Wr1    = (const float*)d_in[8];
    const float* Wl2    = (const float*)d_in[9];
    const float* bl2    = (const float*)d_in[10];
    const float* Wr2    = (const float*)d_in[11];
    const float* W1     = (const float*)d_in[12];
    const float* b1     = (const float*)d_in[13];
    const float* W2     = (const float*)d_in[14];
    const float* b2     = (const float*)d_in[15];
    float* out = (float*)d_out;

    const int N = in_sizes[0] / 128;
    const int E = in_sizes[1] / 2;
    const int P = in_sizes[2];
    const int* src = eidx;
    const int* dst = eidx + E;

    char* ws = (char*)d_ws;
    size_t off = 0;
    auto alloc = [&](size_t bytes) -> void* {
        off = (off + 255) & ~(size_t)255;
        void* p = ws + off;
        off += bytes;
        return p;
    };
    int* row_ptr = (int*)alloc((size_t)(N + 1) * 4);
    int* cursor  = (int*)alloc((size_t)N * 4);
    int* bucket  = (int*)alloc((size_t)E * 4);
    unsigned short* h1 = (unsigned short*)alloc((size_t)N * 256 * 2);
    unsigned short* h2 = (unsigned short*)alloc((size_t)N * 256 * 2);
    char* shared_base = (char*)alloc((size_t)N * 512 * 2);
    unsigned short* xb   = (unsigned short*)shared_base;                         // N*128 bf16
    unsigned short* agg1 = (unsigned short*)(shared_base + (size_t)N * 128 * 2); // N*128 bf16
    unsigned short* agg2 = (unsigned short*)(shared_base + (size_t)N * 256 * 2); // N*256 bf16
    unsigned char*  G2f8 = (unsigned char*)shared_base;                          // N*512 bytes
    unsigned char* xf8  = (unsigned char*)alloc((size_t)N * 128);
    unsigned char* h1f8 = (unsigned char*)alloc((size_t)N * 256);
    unsigned short* Wc1  = (unsigned short*)alloc((size_t)65536 * 2);
    unsigned short* Wc2  = (unsigned short*)alloc((size_t)131072 * 2);
    unsigned short* W1g  = (unsigned short*)alloc((size_t)131072 * 2);
    unsigned short* WaF  = (unsigned short*)alloc((size_t)8192 * 2);

    hipMemsetAsync(cursor, 0, (size_t)N * 4, stream);
    k_count<<<(E + 255) / 256, 256, 0, stream>>>(dst, cursor, E);
    k_scan<<<1, 1024, 0, stream>>>(cursor, row_ptr, N);
    k_scatter<<<(E + 255) / 256, 256, 0, stream>>>(src, dst, cursor, bucket, E);
    k_convert_weights<<<(65536 + 131072 + 131072 + 8192 + 255) / 256, 256, 0, stream>>>(
        Wl1, Wr1, Wl2, Wr2, W1, b1, Wc1, Wc2, W1g, WaF);
    k_xconvert<<<(N * 64 + 255) / 256, 256, 0, stream>>>(x, xb, xf8, N * 128);

    k_agg_x<<<(N + 3) / 4, 256, 0, stream>>>(xf8, row_ptr, bucket, agg1, N);
    dim3 gconv((N + 127) / 128, 2);
    k_conv_gemm<<<gconv, 256, 0, stream>>>(agg1, xb, Wc1, bl1, h1, h1f8, N, 128);
    k_agg_h<<<(N + 3) / 4, 256, 0, stream>>>(h1f8, row_ptr, bucket, agg2, N);
    k_conv_gemm<<<gconv, 256, 0, stream>>>(agg2, h1, Wc2, bl2, h2, (unsigned char*)nullptr, N, 256);

    dim3 gg((N + 127) / 128, 4);
    k_gemm_g<<<gg, 256, 0, stream>>>(h2, W1g, G2f8, N);
    k_edge<<<(P + 63) / 64, 256, 0, stream>>>(G2f8, attr, eu, ev, (const uint4*)WaF,
                                              W2, b2, logexp, out, P);
}

// Round 9
// 466.064 us; speedup vs baseline: 1.1468x; 1.0290x over previous
//
#include <hip/hip_runtime.h>

// GraphSAGE_13993003450942 — round 9:
//  - k_conv_gemm / k_gemm_g staging via __builtin_amdgcn_global_load_lds(16B)
//    (plain lane-order LDS layout; removes VGPR round-trip — the m93->m97 lever)
//  - k_setup fuses count + weight-convert + x-convert (12 -> 9 launches)

typedef float f32x4 __attribute__((ext_vector_type(4)));
typedef float f32x2 __attribute__((ext_vector_type(2)));
typedef __bf16 bf16x8 __attribute__((ext_vector_type(8)));

__device__ __forceinline__ unsigned short f2b(float f) {
    unsigned u = __float_as_uint(f);
    u = u + 0x7fffu + ((u >> 16) & 1u);   // RNE
    return (unsigned short)(u >> 16);
}
__device__ __forceinline__ float b2f(unsigned short s) {
    return __uint_as_float(((unsigned)s) << 16);
}
__device__ __forceinline__ int swz(int r, int g) { return (g + (r >> 1)) & 3; }
__device__ __forceinline__ unsigned char f2f8(float v) {
    return (unsigned char)(__builtin_amdgcn_cvt_pk_fp8_f32(v, v, 0, false) & 0xff);
}
// async 16B global->LDS; LDS dest = (uniform base) + lane*16
__device__ __forceinline__ void gld16(const void* g, void* l) {
    __builtin_amdgcn_global_load_lds((const __attribute__((address_space(1))) void*)g,
                                     (__attribute__((address_space(3))) void*)l, 16, 0, 0);
}

// ---------------- fused setup: edge-count + weight repack + x convert ----------------
// Wc1 [8][256][32] (Wl1|Wr1), Wc2 [16][256][32] (Wl2|Wr2),
// W1g [8][512][32], WaF [16][64][8] (W1a_pad A-frags, b1 folded at k==16)

__global__ void k_setup(const int* __restrict__ dst, int* __restrict__ cnt, int E,
                        const float* __restrict__ Wl1, const float* __restrict__ Wr1,
                        const float* __restrict__ Wl2, const float* __restrict__ Wr2,
                        const float* __restrict__ W1, const float* __restrict__ b1,
                        unsigned short* __restrict__ Wc1, unsigned short* __restrict__ Wc2,
                        unsigned short* __restrict__ W1g, unsigned short* __restrict__ WaF,
                        const float* __restrict__ x, unsigned short* __restrict__ xb,
                        unsigned char* __restrict__ xf8, int nx,
                        int nbCount, int nbConv) {
    int b = blockIdx.x;
    if (b < nbCount) {
        int e = b * 256 + threadIdx.x;
        if (e < E) atomicAdd(&cnt[dst[e]], 1);
    } else if (b < nbCount + nbConv) {
        int idx = (b - nbCount) * 256 + threadIdx.x;
        if (idx < 65536) {
            int c = idx >> 13, j = (idx >> 5) & 255, kk = idx & 31;
            float v = (c < 4) ? Wl1[j * 128 + c * 32 + kk] : Wr1[j * 128 + (c - 4) * 32 + kk];
            Wc1[idx] = f2b(v);
        } else if (idx < 65536 + 131072) {
            int i2 = idx - 65536;
            int c = i2 >> 13, j = (i2 >> 5) & 255, kk = i2 & 31;
            float v = (c < 8) ? Wl2[j * 256 + c * 32 + kk] : Wr2[j * 256 + (c - 8) * 32 + kk];
            Wc2[i2] = f2b(v);
        } else if (idx < 65536 + 131072 + 131072) {
            int i3 = idx - 65536 - 131072;
            int c = i3 >> 14, j = (i3 >> 5) & 511, kk = i3 & 31;
            float v = (j < 256) ? W1[(size_t)j * 528 + c * 32 + kk]
                                : W1[(size_t)(j - 256) * 528 + 256 + c * 32 + kk];
            W1g[i3] = f2b(v);
        } else if (idx < 65536 + 131072 + 131072 + 8192) {
            int i4 = idx - 65536 - 131072 - 131072;
            int mi = i4 >> 9, l = (i4 >> 3) & 63, j = i4 & 7;
            int m = mi * 16 + (l & 15);
            int k = (l >> 4) * 8 + j;
            float v = (k < 16) ? W1[(size_t)m * 528 + 512 + k] : (k == 16 ? b1[m] : 0.f);
            WaF[i4] = f2b(v);
        }
    } else {
        int j = ((b - nbCount - nbConv) * 256 + threadIdx.x) * 2;
        if (j < nx) {
            float a = x[j], c = x[j + 1];
            xb[j] = f2b(a); xb[j + 1] = f2b(c);
            unsigned p = __builtin_amdgcn_cvt_pk_fp8_f32(a, c, 0, false);
            *reinterpret_cast<unsigned short*>(xf8 + j) = (unsigned short)(p & 0xffffu);
        }
    }
}

// ---------------- CSR scan / scatter ----------------

__global__ __launch_bounds__(1024) void k_scan(int* __restrict__ cnt_cursor,
                                               int* __restrict__ row_ptr, int n) {
    __shared__ int wsum[16];
    __shared__ int carry, wtot;
    int t = threadIdx.x, lane = t & 63, w = t >> 6;
    if (t == 0) carry = 0;
    __syncthreads();
    int nch = (n + 1023) >> 10;
    for (int ch = 0; ch < nch; ++ch) {
        int i = (ch << 10) + t;
        int v = (i < n) ? cnt_cursor[i] : 0;
        int s = v;
        #pragma unroll
        for (int off = 1; off < 64; off <<= 1) {
            int u = __shfl_up(s, off);
            if (lane >= off) s += u;
        }
        if (lane == 63) wsum[w] = s;
        __syncthreads();
        if (t < 16) {
            int vv = wsum[t];
            int s2 = vv;
            #pragma unroll
            for (int off = 1; off < 16; off <<= 1) {
                int u = __shfl_up(s2, off);
                if (t >= off) s2 += u;
            }
            wsum[t] = s2 - vv;
            if (t == 15) wtot = s2;
        }
        __syncthreads();
        int base = carry;
        int incl = s + wsum[w];
        if (i < n) { int ex = base + incl - v; row_ptr[i] = ex; cnt_cursor[i] = ex; }
        __syncthreads();
        if (t == 0) carry = base + wtot;
    }
    __syncthreads();
    if (t == 0) row_ptr[n] = carry;
}

__global__ void k_scatter(const int* __restrict__ src, const int* __restrict__ dst,
                          int* __restrict__ cursor, int* __restrict__ bucket, int E) {
    int e = blockIdx.x * 256 + threadIdx.x;
    if (e < E) {
        int p = atomicAdd(&cursor[dst[e]], 1);
        bucket[p] = src[e];
    }
}

// ---------------- aggregation (mean over in-neighbors, fp8 gather) ----------------

__device__ __forceinline__ void accf8(uint2 v, float* s) {
    f32x2 p0 = __builtin_amdgcn_cvt_pk_f32_fp8(v.x, false);
    f32x2 p1 = __builtin_amdgcn_cvt_pk_f32_fp8(v.x, true);
    f32x2 p2 = __builtin_amdgcn_cvt_pk_f32_fp8(v.y, false);
    f32x2 p3 = __builtin_amdgcn_cvt_pk_f32_fp8(v.y, true);
    s[0] += p0.x; s[1] += p0.y; s[2] += p1.x; s[3] += p1.y;
    s[4] += p2.x; s[5] += p2.y; s[6] += p3.x; s[7] += p3.y;
}

__global__ __launch_bounds__(256) void k_agg_x(const unsigned char* __restrict__ xf8,
                                               const int* __restrict__ row_ptr,
                                               const int* __restrict__ bucket,
                                               unsigned short* __restrict__ agg, int Nn) {
    int node = blockIdx.x * 4 + (threadIdx.x >> 6);
    if (node >= Nn) return;
    int lane = threadIdx.x & 63;
    int q = lane >> 4, c = lane & 15;
    int beg = row_ptr[node], end = row_ptr[node + 1];
    int len = end - beg;
    int lo = beg + ((len * q) >> 2);
    int hi = beg + ((len * (q + 1)) >> 2);
    float s[8] = {0.f,0.f,0.f,0.f,0.f,0.f,0.f,0.f};
    const unsigned char* xp = xf8 + c * 8;
    int e = lo;
    for (; e + 4 <= hi; e += 4) {
        int b0 = bucket[e], b1 = bucket[e + 1], b2 = bucket[e + 2], b3 = bucket[e + 3];
        uint2 v0 = *reinterpret_cast<const uint2*>(xp + (size_t)b0 * 128);
        uint2 v1 = *reinterpret_cast<const uint2*>(xp + (size_t)b1 * 128);
        uint2 v2 = *reinterpret_cast<const uint2*>(xp + (size_t)b2 * 128);
        uint2 v3 = *reinterpret_cast<const uint2*>(xp + (size_t)b3 * 128);
        accf8(v0, s); accf8(v1, s); accf8(v2, s); accf8(v3, s);
    }
    for (; e < hi; ++e)
        accf8(*reinterpret_cast<const uint2*>(xp + (size_t)bucket[e] * 128), s);
    #pragma unroll
    for (int j = 0; j < 8; ++j) {
        s[j] += __shfl_xor(s[j], 16);
        s[j] += __shfl_xor(s[j], 32);
    }
    if (q == 0) {
        float sc = 1.0f / (float)(len > 1 ? len : 1);
        uint4 o;
        o.x = (unsigned)f2b(s[0]*sc) | ((unsigned)f2b(s[1]*sc) << 16);
        o.y = (unsigned)f2b(s[2]*sc) | ((unsigned)f2b(s[3]*sc) << 16);
        o.z = (unsigned)f2b(s[4]*sc) | ((unsigned)f2b(s[5]*sc) << 16);
        o.w = (unsigned)f2b(s[6]*sc) | ((unsigned)f2b(s[7]*sc) << 16);
        *reinterpret_cast<uint4*>(agg + (size_t)node * 128 + c * 8) = o;
    }
}

__global__ __launch_bounds__(256) void k_agg_h(const unsigned char* __restrict__ hf8,
                                               const int* __restrict__ row_ptr,
                                               const int* __restrict__ bucket,
                                               unsigned short* __restrict__ agg, int Nn) {
    int node = blockIdx.x * 4 + (threadIdx.x >> 6);
    if (node >= Nn) return;
    int lane = threadIdx.x & 63;
    int g = lane >> 5, c = lane & 31;
    int beg = row_ptr[node], end = row_ptr[node + 1];
    int len = end - beg;
    int lo = beg + ((len * g) >> 1);
    int hi = beg + ((len * (g + 1)) >> 1);
    float s[8] = {0.f,0.f,0.f,0.f,0.f,0.f,0.f,0.f};
    const unsigned char* hp = hf8 + c * 8;
    int e = lo;
    for (; e + 4 <= hi; e += 4) {
        int b0 = bucket[e], b1 = bucket[e + 1], b2 = bucket[e + 2], b3 = bucket[e + 3];
        uint2 v0 = *reinterpret_cast<const uint2*>(hp + (size_t)b0 * 256);
        uint2 v1 = *reinterpret_cast<const uint2*>(hp + (size_t)b1 * 256);
        uint2 v2 = *reinterpret_cast<const uint2*>(hp + (size_t)b2 * 256);
        uint2 v3 = *reinterpret_cast<const uint2*>(hp + (size_t)b3 * 256);
        accf8(v0, s); accf8(v1, s); accf8(v2, s); accf8(v3, s);
    }
    for (; e < hi; ++e)
        accf8(*reinterpret_cast<const uint2*>(hp + (size_t)bucket[e] * 256), s);
    #pragma unroll
    for (int j = 0; j < 8; ++j) s[j] += __shfl_xor(s[j], 32);
    if (g == 0) {
        float sc = 1.0f / (float)(len > 1 ? len : 1);
        uint4 o;
        o.x = (unsigned)f2b(s[0]*sc) | ((unsigned)f2b(s[1]*sc) << 16);
        o.y = (unsigned)f2b(s[2]*sc) | ((unsigned)f2b(s[3]*sc) << 16);
        o.z = (unsigned)f2b(s[4]*sc) | ((unsigned)f2b(s[5]*sc) << 16);
        o.w = (unsigned)f2b(s[6]*sc) | ((unsigned)f2b(s[7]*sc) << 16);
        *reinterpret_cast<uint4*>(agg + (size_t)node * 256 + c * 8) = o;
    }
}

// ---------------- conv GEMM: H = relu(bias + Aagg@Wl^T + Aself@Wr^T) ----------------
// global_load_lds(16) staging, plain lane-order LDS layout (no swizzle).

__global__ __launch_bounds__(256) void k_conv_gemm(const unsigned short* __restrict__ Aagg,
                                                   const unsigned short* __restrict__ Aself,
                                                   const unsigned short* __restrict__ Wck,
                                                   const float* __restrict__ bias,
                                                   unsigned short* __restrict__ Hout,
                                                   unsigned char* __restrict__ Hf8,
                                                   int Nn, int F) {
    __shared__ __align__(16) unsigned short zt[128 * 32];
    __shared__ __align__(16) unsigned short wt[128 * 32];
    const int t = threadIdx.x;
    const int lane = t & 63, w = t >> 6;
    const int wm = w >> 1, wn = w & 1;
    const int node0 = blockIdx.x * 128;
    const int colh = blockIdx.y;
    const int half = F >> 5, nchunks = F >> 4;

    f32x4 acc[4][4];
    #pragma unroll
    for (int i = 0; i < 4; ++i)
        #pragma unroll
        for (int j = 0; j < 4; ++j) acc[i][j] = (f32x4){0.f, 0.f, 0.f, 0.f};

    for (int c = 0; c < nchunks; ++c) {
        __syncthreads();
        const unsigned short* Asrc = (c < half) ? Aagg : Aself;
        const int ccol = ((c < half) ? c : c - half) * 32;
        #pragma unroll
        for (int j = 0; j < 2; ++j) {
            int fc = (w * 2 + j) * 64 + lane;
            int row = fc >> 2, seg = fc & 3;
            int node = node0 + row; if (node >= Nn) node = Nn - 1;
            gld16(Asrc + (size_t)node * F + ccol + seg * 8, &zt[(w * 2 + j) * 512]);
        }
        const unsigned short* Wsrc = Wck + ((size_t)c * 256 + colh * 128) * 32;
        #pragma unroll
        for (int j = 0; j < 2; ++j) {
            int fc = (w * 2 + j) * 64 + lane;
            gld16(Wsrc + fc * 8, &wt[(w * 2 + j) * 512]);
        }
        __syncthreads();
        bf16x8 a[4], b[4];
        const int q = lane >> 4;
        #pragma unroll
        for (int mi = 0; mi < 4; ++mi) {
            int R = wm * 64 + mi * 16 + (lane & 15);
            a[mi] = *reinterpret_cast<const bf16x8*>(&zt[R * 32 + q * 8]);
        }
        #pragma unroll
        for (int ni = 0; ni < 4; ++ni) {
            int R = wn * 64 + ni * 16 + (lane & 15);
            b[ni] = *reinterpret_cast<const bf16x8*>(&wt[R * 32 + q * 8]);
        }
        #pragma unroll
        for (int mi = 0; mi < 4; ++mi)
            #pragma unroll
            for (int ni = 0; ni < 4; ++ni)
                acc[mi][ni] = __builtin_amdgcn_mfma_f32_16x16x32_bf16(a[mi], b[ni], acc[mi][ni], 0, 0, 0);
    }

    #pragma unroll
    for (int mi = 0; mi < 4; ++mi)
        #pragma unroll
        for (int ni = 0; ni < 4; ++ni) {
            int col = colh * 128 + wn * 64 + ni * 16 + (lane & 15);
            float bia = bias[col];
            #pragma unroll
            for (int r = 0; r < 4; ++r) {
                int row = node0 + wm * 64 + mi * 16 + ((lane >> 4) << 2) + r;
                if (row < Nn) {
                    float v = acc[mi][ni][r] + bia;
                    v = v > 0.f ? v : 0.f;
                    Hout[(size_t)row * 256 + col] = f2b(v);
                    if (Hf8) Hf8[(size_t)row * 256 + col] = f2f8(v);
                }
            }
        }
}

// ---------------- G GEMM: G2f8 = fp8(h2 @ [W1u;W1v]^T)  ([N][512] bytes) ----------------

__global__ __launch_bounds__(256) void k_gemm_g(const unsigned short* __restrict__ A,
                                                const unsigned short* __restrict__ Wck,
                                                unsigned char* __restrict__ Gout,
                                                int Nn) {
    __shared__ __align__(16) unsigned short zt[128 * 32];
    __shared__ __align__(16) unsigned short wt[128 * 32];
    const int t = threadIdx.x;
    const int lane = t & 63, w = t >> 6;
    const int wm = w >> 1, wn = w & 1;
    const int node0 = blockIdx.x * 128;
    const int colg = blockIdx.y;

    f32x4 acc[4][4];
    #pragma unroll
    for (int i = 0; i < 4; ++i)
        #pragma unroll
        for (int j = 0; j < 4; ++j) acc[i][j] = (f32x4){0.f, 0.f, 0.f, 0.f};

    for (int c = 0; c < 8; ++c) {
        __syncthreads();
        #pragma unroll
        for (int j = 0; j < 2; ++j) {
            int fc = (w * 2 + j) * 64 + lane;
            int row = fc >> 2, seg = fc & 3;
            int node = node0 + row; if (node >= Nn) node = Nn - 1;
            gld16(A + (size_t)node * 256 + c * 32 + seg * 8, &zt[(w * 2 + j) * 512]);
        }
        const unsigned short* Wsrc = Wck + ((size_t)c * 512 + colg * 128) * 32;
        #pragma unroll
        for (int j = 0; j < 2; ++j) {
            int fc = (w * 2 + j) * 64 + lane;
            gld16(Wsrc + fc * 8, &wt[(w * 2 + j) * 512]);
        }
        __syncthreads();
        bf16x8 a[4], b[4];
        const int q = lane >> 4;
        #pragma unroll
        for (int mi = 0; mi < 4; ++mi) {
            int R = wm * 64 + mi * 16 + (lane & 15);
            a[mi] = *reinterpret_cast<const bf16x8*>(&zt[R * 32 + q * 8]);
        }
        #pragma unroll
        for (int ni = 0; ni < 4; ++ni) {
            int R = wn * 64 + ni * 16 + (lane & 15);
            b[ni] = *reinterpret_cast<const bf16x8*>(&wt[R * 32 + q * 8]);
        }
        #pragma unroll
        for (int mi = 0; mi < 4; ++mi)
            #pragma unroll
            for (int ni = 0; ni < 4; ++ni)
                acc[mi][ni] = __builtin_amdgcn_mfma_f32_16x16x32_bf16(a[mi], b[ni], acc[mi][ni], 0, 0, 0);
    }

    #pragma unroll
    for (int mi = 0; mi < 4; ++mi)
        #pragma unroll
        for (int ni = 0; ni < 4; ++ni) {
            int col = colg * 128 + wn * 64 + ni * 16 + (lane & 15);
            #pragma unroll
            for (int r = 0; r < 4; ++r) {
                int row = node0 + wm * 64 + mi * 16 + ((lane >> 4) << 2) + r;
                if (row < Nn)
                    Gout[(size_t)row * 512 + col] = f2f8(acc[mi][ni][r]);
            }
        }
}

// ---------------- edge kernel v5 (fp8 G2) ----------------

__global__ __launch_bounds__(256, 6) void k_edge(const unsigned char* __restrict__ G2,
                                                 const float* __restrict__ attr,
                                                 const int* __restrict__ eu,
                                                 const int* __restrict__ ev,
                                                 const uint4* __restrict__ WaF,
                                                 const float* __restrict__ W2,
                                                 const float* __restrict__ b2,
                                                 const float* __restrict__ logexp,
                                                 float* __restrict__ out, int P) {
    __shared__ __align__(16) unsigned short attrT[64 * 40];
    __shared__ __align__(16) unsigned char gt[64 * 264];
    __shared__ float w2s[256];
    __shared__ int euv[128];
    const int t = threadIdx.x;
    const int lane = t & 63, w = t >> 6;
    const int base = blockIdx.x * 64;

    {
        int e = t >> 2, seg = t & 3;
        int eg = base + e; if (eg >= P) eg = P - 1;
        const float4 f = *reinterpret_cast<const float4*>(attr + (size_t)eg * 16 + seg * 4);
        uint2 o;
        o.x = (unsigned)f2b(f.x) | ((unsigned)f2b(f.y) << 16);
        o.y = (unsigned)f2b(f.z) | ((unsigned)f2b(f.w) << 16);
        *reinterpret_cast<uint2*>(&attrT[e * 40 + seg * 4]) = o;
    }
    if (t < 64) {
        uint2 z0; z0.x = 0x3f80u; z0.y = 0u;
        *reinterpret_cast<uint2*>(&attrT[t * 40 + 16]) = z0;
        uint2 z1; z1.x = 0u; z1.y = 0u;
        *reinterpret_cast<uint2*>(&attrT[t * 40 + 20]) = z1;
        uint4 z2; z2.x = z2.y = z2.z = z2.w = 0u;
        *reinterpret_cast<uint4*>(&attrT[t * 40 + 24]) = z2;
    }
    if (t < 128) {
        int e = t >> 1;
        int eg = base + e; if (eg >= P) eg = P - 1;
        euv[t] = (t & 1) ? ev[eg] : eu[eg];
    }
    w2s[t] = W2[t];
    __syncthreads();

    const int el = lane & 15, q = lane >> 4;
    const int grow = w * 16 + el;
    const bf16x8 bfrag = *reinterpret_cast<const bf16x8*>(&attrT[grow * 40 + q * 8]);

    float s = 0.f;
    #pragma unroll
    for (int p = 0; p < 2; ++p) {
        {
            const int sub = lane >> 4, c = lane & 15;
            #pragma unroll
            for (int i = 0; i < 4; ++i) {
                int le = w * 16 + i * 4 + sub;
                int u = euv[2 * le], v = euv[2 * le + 1];
                uint2 a = *reinterpret_cast<const uint2*>(G2 + (size_t)u * 512 + p * 128 + c * 8);
                uint2 b = *reinterpret_cast<const uint2*>(G2 + (size_t)v * 512 + 256 + p * 128 + c * 8);
                *reinterpret_cast<uint2*>(&gt[le * 264 + c * 8]) = a;
                *reinterpret_cast<uint2*>(&gt[le * 264 + 128 + c * 8]) = b;
            }
        }
        #pragma unroll
        for (int m = 0; m < 8; ++m) {
            const int mi = p * 8 + m;
            const bf16x8 af = *reinterpret_cast<const bf16x8*>(&WaF[mi * 64 + lane]);
            f32x4 acc = __builtin_amdgcn_mfma_f32_16x16x32_bf16(af, bfrag, (f32x4){0.f,0.f,0.f,0.f}, 0, 0, 0);
            const unsigned gu4 = *reinterpret_cast<const unsigned*>(&gt[grow * 264 + m * 16 + q * 4]);
            const unsigned gv4 = *reinterpret_cast<const unsigned*>(&gt[grow * 264 + 128 + m * 16 + q * 4]);
            const float4 w2v = *reinterpret_cast<const float4*>(&w2s[mi * 16 + q * 4]);
            f32x2 ulo = __builtin_amdgcn_cvt_pk_f32_fp8(gu4, false);
            f32x2 uhi = __builtin_amdgcn_cvt_pk_f32_fp8(gu4, true);
            f32x2 vlo = __builtin_amdgcn_cvt_pk_f32_fp8(gv4, false);
            f32x2 vhi = __builtin_amdgcn_cvt_pk_f32_fp8(gv4, true);
            float y0 = acc[0] + ulo.x + vlo.x;
            float y1 = acc[1] + ulo.y + vlo.y;
            float y2 = acc[2] + uhi.x + vhi.x;
            float y3 = acc[3] + uhi.y + vhi.y;
            s += (y0 > 0.f ? y0 : 0.f) * w2v.x;
            s += (y1 > 0.f ? y1 : 0.f) * w2v.y;
            s += (y2 > 0.f ? y2 : 0.f) * w2v.z;
            s += (y3 > 0.f ? y3 : 0.f) * w2v.w;
        }
        if (p == 0) __syncthreads();
    }
    s += __shfl_xor(s, 16);
    s += __shfl_xor(s, 32);
    int eg = base + grow;
    if (q == 0 && eg < P)
        out[eg] = logexp[eg] + b2[0] + s;
}

// ---------------- launch ----------------

extern "C" void kernel_launch(void* const* d_in, const int* in_sizes, int n_in,
                              void* d_out, int out_size, void* d_ws, size_t ws_size,
                              hipStream_t stream) {
    const float* x      = (const float*)d_in[0];
    const int*   eidx   = (const int*)d_in[1];
    const int*   eu     = (const int*)d_in[2];
    const int*   ev     = (const int*)d_in[3];
    const float* attr   = (const float*)d_in[4];
    const float* logexp = (const float*)d_in[5];
    const float* Wl1    = (const float*)d_in[6];
    const float* bl1    = (const float*)d_in[7];
    const float* Wr1    = (const float*)d_in[8];
    const float* Wl2    = (const float*)d_in[9];
    const float* bl2    = (const float*)d_in[10];
    const float* Wr2    = (const float*)d_in[11];
    const float* W1     = (const float*)d_in[12];
    const float* b1     = (const float*)d_in[13];
    const float* W2     = (const float*)d_in[14];
    const float* b2     = (const float*)d_in[15];
    float* out = (float*)d_out;

    const int N = in_sizes[0] / 128;
    const int E = in_sizes[1] / 2;
    const int P = in_sizes[2];
    const int* src = eidx;
    const int* dst = eidx + E;

    char* ws = (char*)d_ws;
    size_t off = 0;
    auto alloc = [&](size_t bytes) -> void* {
        off = (off + 255) & ~(size_t)255;
        void* p = ws + off;
        off += bytes;
        return p;
    };
    int* row_ptr = (int*)alloc((size_t)(N + 1) * 4);
    int* cursor  = (int*)alloc((size_t)N * 4);
    int* bucket  = (int*)alloc((size_t)E * 4);
    unsigned short* h1 = (unsigned short*)alloc((size_t)N * 256 * 2);
    unsigned short* h2 = (unsigned short*)alloc((size_t)N * 256 * 2);
    char* shared_base = (char*)alloc((size_t)N * 512 * 2);
    unsigned short* xb   = (unsigned short*)shared_base;                         // N*128 bf16
    unsigned short* agg1 = (unsigned short*)(shared_base + (size_t)N * 128 * 2); // N*128 bf16
    unsigned short* agg2 = (unsigned short*)(shared_base + (size_t)N * 256 * 2); // N*256 bf16
    unsigned char*  G2f8 = (unsigned char*)shared_base;                          // N*512 bytes
    unsigned char* xf8  = (unsigned char*)alloc((size_t)N * 128);
    unsigned char* h1f8 = (unsigned char*)alloc((size_t)N * 256);
    unsigned short* Wc1  = (unsigned short*)alloc((size_t)65536 * 2);
    unsigned short* Wc2  = (unsigned short*)alloc((size_t)131072 * 2);
    unsigned short* W1g  = (unsigned short*)alloc((size_t)131072 * 2);
    unsigned short* WaF  = (unsigned short*)alloc((size_t)8192 * 2);

    hipMemsetAsync(cursor, 0, (size_t)N * 4, stream);
    const int nbCount = (E + 255) / 256;
    const int nbConv  = (65536 + 131072 + 131072 + 8192 + 255) / 256;
    const int nbX     = (N * 64 + 255) / 256;
    k_setup<<<nbCount + nbConv + nbX, 256, 0, stream>>>(
        dst, cursor, E, Wl1, Wr1, Wl2, Wr2, W1, b1, Wc1, Wc2, W1g, WaF,
        x, xb, xf8, N * 128, nbCount, nbConv);
    k_scan<<<1, 1024, 0, stream>>>(cursor, row_ptr, N);
    k_scatter<<<(E + 255) / 256, 256, 0, stream>>>(src, dst, cursor, bucket, E);

    k_agg_x<<<(N + 3) / 4, 256, 0, stream>>>(xf8, row_ptr, bucket, agg1, N);
    dim3 gconv((N + 127) / 128, 2);
    k_conv_gemm<<<gconv, 256, 0, stream>>>(agg1, xb, Wc1, bl1, h1, h1f8, N, 128);
    k_agg_h<<<(N + 3) / 4, 256, 0, stream>>>(h1f8, row_ptr, bucket, agg2, N);
    k_conv_gemm<<<gconv, 256, 0, stream>>>(agg2, h1, Wc2, bl2, h2, (unsigned char*)nullptr, N, 256);

    dim3 gg((N + 127) / 128, 4);
    k_gemm_g<<<gg, 256, 0, stream>>>(h2, W1g, G2f8, N);
    k_edge<<<(P + 63) / 64, 256, 0, stream>>>(G2f8, attr, eu, ev, (const uint4*)WaF,
                                              W2, b2, logexp, out, P);
}

// Round 10
// 432.026 us; speedup vs baseline: 1.2371x; 1.0788x over previous
//
#include <hip/hip_runtime.h>

// GraphSAGE_13993003450942 — round 10:
//  - 512-thread GEMM blocks (2x4 waves, full 256-col coverage): A-tile staged
//    once per K-chunk (conv y 2->1, gemm_g y 4->2; saves ~128 MB restaging)
//  - everything else identical to round 9 (fp8 aggs, fp8 G2, k_edge v5)

typedef float f32x4 __attribute__((ext_vector_type(4)));
typedef float f32x2 __attribute__((ext_vector_type(2)));
typedef __bf16 bf16x8 __attribute__((ext_vector_type(8)));

__device__ __forceinline__ unsigned short f2b(float f) {
    unsigned u = __float_as_uint(f);
    u = u + 0x7fffu + ((u >> 16) & 1u);   // RNE
    return (unsigned short)(u >> 16);
}
__device__ __forceinline__ float b2f(unsigned short s) {
    return __uint_as_float(((unsigned)s) << 16);
}
__device__ __forceinline__ unsigned char f2f8(float v) {
    return (unsigned char)(__builtin_amdgcn_cvt_pk_fp8_f32(v, v, 0, false) & 0xff);
}
// async 16B global->LDS; LDS dest = (uniform base) + lane*16
__device__ __forceinline__ void gld16(const void* g, void* l) {
    __builtin_amdgcn_global_load_lds((const __attribute__((address_space(1))) void*)g,
                                     (__attribute__((address_space(3))) void*)l, 16, 0, 0);
}

// ---------------- fused setup: edge-count + weight repack + x convert ----------------

__global__ void k_setup(const int* __restrict__ dst, int* __restrict__ cnt, int E,
                        const float* __restrict__ Wl1, const float* __restrict__ Wr1,
                        const float* __restrict__ Wl2, const float* __restrict__ Wr2,
                        const float* __restrict__ W1, const float* __restrict__ b1,
                        unsigned short* __restrict__ Wc1, unsigned short* __restrict__ Wc2,
                        unsigned short* __restrict__ W1g, unsigned short* __restrict__ WaF,
                        const float* __restrict__ x, unsigned short* __restrict__ xb,
                        unsigned char* __restrict__ xf8, int nx,
                        int nbCount, int nbConv) {
    int b = blockIdx.x;
    if (b < nbCount) {
        int e = b * 256 + threadIdx.x;
        if (e < E) atomicAdd(&cnt[dst[e]], 1);
    } else if (b < nbCount + nbConv) {
        int idx = (b - nbCount) * 256 + threadIdx.x;
        if (idx < 65536) {
            int c = idx >> 13, j = (idx >> 5) & 255, kk = idx & 31;
            float v = (c < 4) ? Wl1[j * 128 + c * 32 + kk] : Wr1[j * 128 + (c - 4) * 32 + kk];
            Wc1[idx] = f2b(v);
        } else if (idx < 65536 + 131072) {
            int i2 = idx - 65536;
            int c = i2 >> 13, j = (i2 >> 5) & 255, kk = i2 & 31;
            float v = (c < 8) ? Wl2[j * 256 + c * 32 + kk] : Wr2[j * 256 + (c - 8) * 32 + kk];
            Wc2[i2] = f2b(v);
        } else if (idx < 65536 + 131072 + 131072) {
            int i3 = idx - 65536 - 131072;
            int c = i3 >> 14, j = (i3 >> 5) & 511, kk = i3 & 31;
            float v = (j < 256) ? W1[(size_t)j * 528 + c * 32 + kk]
                                : W1[(size_t)(j - 256) * 528 + 256 + c * 32 + kk];
            W1g[i3] = f2b(v);
        } else if (idx < 65536 + 131072 + 131072 + 8192) {
            int i4 = idx - 65536 - 131072 - 131072;
            int mi = i4 >> 9, l = (i4 >> 3) & 63, j = i4 & 7;
            int m = mi * 16 + (l & 15);
            int k = (l >> 4) * 8 + j;
            float v = (k < 16) ? W1[(size_t)m * 528 + 512 + k] : (k == 16 ? b1[m] : 0.f);
            WaF[i4] = f2b(v);
        }
    } else {
        int j = ((b - nbCount - nbConv) * 256 + threadIdx.x) * 2;
        if (j < nx) {
            float a = x[j], c = x[j + 1];
            xb[j] = f2b(a); xb[j + 1] = f2b(c);
            unsigned p = __builtin_amdgcn_cvt_pk_fp8_f32(a, c, 0, false);
            *reinterpret_cast<unsigned short*>(xf8 + j) = (unsigned short)(p & 0xffffu);
        }
    }
}

// ---------------- CSR scan / scatter ----------------

__global__ __launch_bounds__(1024) void k_scan(int* __restrict__ cnt_cursor,
                                               int* __restrict__ row_ptr, int n) {
    __shared__ int wsum[16];
    __shared__ int carry, wtot;
    int t = threadIdx.x, lane = t & 63, w = t >> 6;
    if (t == 0) carry = 0;
    __syncthreads();
    int nch = (n + 1023) >> 10;
    for (int ch = 0; ch < nch; ++ch) {
        int i = (ch << 10) + t;
        int v = (i < n) ? cnt_cursor[i] : 0;
        int s = v;
        #pragma unroll
        for (int off = 1; off < 64; off <<= 1) {
            int u = __shfl_up(s, off);
            if (lane >= off) s += u;
        }
        if (lane == 63) wsum[w] = s;
        __syncthreads();
        if (t < 16) {
            int vv = wsum[t];
            int s2 = vv;
            #pragma unroll
            for (int off = 1; off < 16; off <<= 1) {
                int u = __shfl_up(s2, off);
                if (t >= off) s2 += u;
            }
            wsum[t] = s2 - vv;
            if (t == 15) wtot = s2;
        }
        __syncthreads();
        int base = carry;
        int incl = s + wsum[w];
        if (i < n) { int ex = base + incl - v; row_ptr[i] = ex; cnt_cursor[i] = ex; }
        __syncthreads();
        if (t == 0) carry = base + wtot;
    }
    __syncthreads();
    if (t == 0) row_ptr[n] = carry;
}

__global__ void k_scatter(const int* __restrict__ src, const int* __restrict__ dst,
                          int* __restrict__ cursor, int* __restrict__ bucket, int E) {
    int e = blockIdx.x * 256 + threadIdx.x;
    if (e < E) {
        int p = atomicAdd(&cursor[dst[e]], 1);
        bucket[p] = src[e];
    }
}

// ---------------- aggregation (mean over in-neighbors, fp8 gather) ----------------

__device__ __forceinline__ void accf8(uint2 v, float* s) {
    f32x2 p0 = __builtin_amdgcn_cvt_pk_f32_fp8(v.x, false);
    f32x2 p1 = __builtin_amdgcn_cvt_pk_f32_fp8(v.x, true);
    f32x2 p2 = __builtin_amdgcn_cvt_pk_f32_fp8(v.y, false);
    f32x2 p3 = __builtin_amdgcn_cvt_pk_f32_fp8(v.y, true);
    s[0] += p0.x; s[1] += p0.y; s[2] += p1.x; s[3] += p1.y;
    s[4] += p2.x; s[5] += p2.y; s[6] += p3.x; s[7] += p3.y;
}

__global__ __launch_bounds__(256) void k_agg_x(const unsigned char* __restrict__ xf8,
                                               const int* __restrict__ row_ptr,
                                               const int* __restrict__ bucket,
                                               unsigned short* __restrict__ agg, int Nn) {
    int node = blockIdx.x * 4 + (threadIdx.x >> 6);
    if (node >= Nn) return;
    int lane = threadIdx.x & 63;
    int q = lane >> 4, c = lane & 15;
    int beg = row_ptr[node], end = row_ptr[node + 1];
    int len = end - beg;
    int lo = beg + ((len * q) >> 2);
    int hi = beg + ((len * (q + 1)) >> 2);
    float s[8] = {0.f,0.f,0.f,0.f,0.f,0.f,0.f,0.f};
    const unsigned char* xp = xf8 + c * 8;
    int e = lo;
    for (; e + 4 <= hi; e += 4) {
        int b0 = bucket[e], b1 = bucket[e + 1], b2 = bucket[e + 2], b3 = bucket[e + 3];
        uint2 v0 = *reinterpret_cast<const uint2*>(xp + (size_t)b0 * 128);
        uint2 v1 = *reinterpret_cast<const uint2*>(xp + (size_t)b1 * 128);
        uint2 v2 = *reinterpret_cast<const uint2*>(xp + (size_t)b2 * 128);
        uint2 v3 = *reinterpret_cast<const uint2*>(xp + (size_t)b3 * 128);
        accf8(v0, s); accf8(v1, s); accf8(v2, s); accf8(v3, s);
    }
    for (; e < hi; ++e)
        accf8(*reinterpret_cast<const uint2*>(xp + (size_t)bucket[e] * 128), s);
    #pragma unroll
    for (int j = 0; j < 8; ++j) {
        s[j] += __shfl_xor(s[j], 16);
        s[j] += __shfl_xor(s[j], 32);
    }
    if (q == 0) {
        float sc = 1.0f / (float)(len > 1 ? len : 1);
        uint4 o;
        o.x = (unsigned)f2b(s[0]*sc) | ((unsigned)f2b(s[1]*sc) << 16);
        o.y = (unsigned)f2b(s[2]*sc) | ((unsigned)f2b(s[3]*sc) << 16);
        o.z = (unsigned)f2b(s[4]*sc) | ((unsigned)f2b(s[5]*sc) << 16);
        o.w = (unsigned)f2b(s[6]*sc) | ((unsigned)f2b(s[7]*sc) << 16);
        *reinterpret_cast<uint4*>(agg + (size_t)node * 128 + c * 8) = o;
    }
}

__global__ __launch_bounds__(256) void k_agg_h(const unsigned char* __restrict__ hf8,
                                               const int* __restrict__ row_ptr,
                                               const int* __restrict__ bucket,
                                               unsigned short* __restrict__ agg, int Nn) {
    int node = blockIdx.x * 4 + (threadIdx.x >> 6);
    if (node >= Nn) return;
    int lane = threadIdx.x & 63;
    int g = lane >> 5, c = lane & 31;
    int beg = row_ptr[node], end = row_ptr[node + 1];
    int len = end - beg;
    int lo = beg + ((len * g) >> 1);
    int hi = beg + ((len * (g + 1)) >> 1);
    float s[8] = {0.f,0.f,0.f,0.f,0.f,0.f,0.f,0.f};
    const unsigned char* hp = hf8 + c * 8;
    int e = lo;
    for (; e + 4 <= hi; e += 4) {
        int b0 = bucket[e], b1 = bucket[e + 1], b2 = bucket[e + 2], b3 = bucket[e + 3];
        uint2 v0 = *reinterpret_cast<const uint2*>(hp + (size_t)b0 * 256);
        uint2 v1 = *reinterpret_cast<const uint2*>(hp + (size_t)b1 * 256);
        uint2 v2 = *reinterpret_cast<const uint2*>(hp + (size_t)b2 * 256);
        uint2 v3 = *reinterpret_cast<const uint2*>(hp + (size_t)b3 * 256);
        accf8(v0, s); accf8(v1, s); accf8(v2, s); accf8(v3, s);
    }
    for (; e < hi; ++e)
        accf8(*reinterpret_cast<const uint2*>(hp + (size_t)bucket[e] * 256), s);
    #pragma unroll
    for (int j = 0; j < 8; ++j) s[j] += __shfl_xor(s[j], 32);
    if (g == 0) {
        float sc = 1.0f / (float)(len > 1 ? len : 1);
        uint4 o;
        o.x = (unsigned)f2b(s[0]*sc) | ((unsigned)f2b(s[1]*sc) << 16);
        o.y = (unsigned)f2b(s[2]*sc) | ((unsigned)f2b(s[3]*sc) << 16);
        o.z = (unsigned)f2b(s[4]*sc) | ((unsigned)f2b(s[5]*sc) << 16);
        o.w = (unsigned)f2b(s[6]*sc) | ((unsigned)f2b(s[7]*sc) << 16);
        *reinterpret_cast<uint4*>(agg + (size_t)node * 256 + c * 8) = o;
    }
}

// ---------------- conv GEMM (512 thr, full 256-col tile): H = relu(b + Aagg@Wl^T + Aself@Wr^T) ----------------
// 8 waves (2 row x 4 col); A staged ONCE per chunk; global_load_lds(16) staging.

__global__ __launch_bounds__(512) void k_conv_gemm(const unsigned short* __restrict__ Aagg,
                                                   const unsigned short* __restrict__ Aself,
                                                   const unsigned short* __restrict__ Wck,
                                                   const float* __restrict__ bias,
                                                   unsigned short* __restrict__ Hout,
                                                   unsigned char* __restrict__ Hf8,
                                                   int Nn, int F) {
    __shared__ __align__(16) unsigned short zt[128 * 32];   // A tile 128 rows x 32 k
    __shared__ __align__(16) unsigned short wt[256 * 32];   // W tile 256 rows x 32 k
    const int t = threadIdx.x;
    const int lane = t & 63, w = t >> 6;
    const int wm = w >> 2, wn = w & 3;
    const int node0 = blockIdx.x * 128;
    const int half = F >> 5, nchunks = F >> 4;

    f32x4 acc[4][4];
    #pragma unroll
    for (int i = 0; i < 4; ++i)
        #pragma unroll
        for (int j = 0; j < 4; ++j) acc[i][j] = (f32x4){0.f, 0.f, 0.f, 0.f};

    for (int c = 0; c < nchunks; ++c) {
        __syncthreads();
        const unsigned short* Asrc = (c < half) ? Aagg : Aself;
        const int ccol = ((c < half) ? c : c - half) * 32;
        {   // A: 8 KB = 512 lanes x 16B, one call per wave
            int fc = t;                       // fc = w*64+lane
            int row = fc >> 2, seg = fc & 3;
            int node = node0 + row; if (node >= Nn) node = Nn - 1;
            gld16(Asrc + (size_t)node * F + ccol + seg * 8, &zt[w * 512]);
        }
        const unsigned short* Wsrc = Wck + (size_t)c * 256 * 32;
        #pragma unroll
        for (int j = 0; j < 2; ++j) {         // W: 16 KB = 2 calls per wave
            int fc = (w * 2 + j) * 64 + lane;
            gld16(Wsrc + fc * 8, &wt[(w * 2 + j) * 512]);
        }
        __syncthreads();
        bf16x8 a[4], b[4];
        const int q = lane >> 4;
        #pragma unroll
        for (int mi = 0; mi < 4; ++mi) {
            int R = wm * 64 + mi * 16 + (lane & 15);
            a[mi] = *reinterpret_cast<const bf16x8*>(&zt[R * 32 + q * 8]);
        }
        #pragma unroll
        for (int ni = 0; ni < 4; ++ni) {
            int R = wn * 64 + ni * 16 + (lane & 15);
            b[ni] = *reinterpret_cast<const bf16x8*>(&wt[R * 32 + q * 8]);
        }
        #pragma unroll
        for (int mi = 0; mi < 4; ++mi)
            #pragma unroll
            for (int ni = 0; ni < 4; ++ni)
                acc[mi][ni] = __builtin_amdgcn_mfma_f32_16x16x32_bf16(a[mi], b[ni], acc[mi][ni], 0, 0, 0);
    }

    #pragma unroll
    for (int mi = 0; mi < 4; ++mi)
        #pragma unroll
        for (int ni = 0; ni < 4; ++ni) {
            int col = wn * 64 + ni * 16 + (lane & 15);
            float bia = bias[col];
            #pragma unroll
            for (int r = 0; r < 4; ++r) {
                int row = node0 + wm * 64 + mi * 16 + ((lane >> 4) << 2) + r;
                if (row < Nn) {
                    float v = acc[mi][ni][r] + bia;
                    v = v > 0.f ? v : 0.f;
                    Hout[(size_t)row * 256 + col] = f2b(v);
                    if (Hf8) Hf8[(size_t)row * 256 + col] = f2f8(v);
                }
            }
        }
}

// ---------------- G GEMM (512 thr, 256-col tile, y=2): G2f8 = fp8(h2 @ [W1u;W1v]^T) ----------------

__global__ __launch_bounds__(512) void k_gemm_g(const unsigned short* __restrict__ A,
                                                const unsigned short* __restrict__ Wck,
                                                unsigned char* __restrict__ Gout,
                                                int Nn) {
    __shared__ __align__(16) unsigned short zt[128 * 32];
    __shared__ __align__(16) unsigned short wt[256 * 32];
    const int t = threadIdx.x;
    const int lane = t & 63, w = t >> 6;
    const int wm = w >> 2, wn = w & 3;
    const int node0 = blockIdx.x * 128;
    const int colg = blockIdx.y;              // 0/1 -> 256-col half of 512

    f32x4 acc[4][4];
    #pragma unroll
    for (int i = 0; i < 4; ++i)
        #pragma unroll
        for (int j = 0; j < 4; ++j) acc[i][j] = (f32x4){0.f, 0.f, 0.f, 0.f};

    for (int c = 0; c < 8; ++c) {
        __syncthreads();
        {
            int fc = t;
            int row = fc >> 2, seg = fc & 3;
            int node = node0 + row; if (node >= Nn) node = Nn - 1;
            gld16(A + (size_t)node * 256 + c * 32 + seg * 8, &zt[w * 512]);
        }
        const unsigned short* Wsrc = Wck + ((size_t)c * 512 + colg * 256) * 32;
        #pragma unroll
        for (int j = 0; j < 2; ++j) {
            int fc = (w * 2 + j) * 64 + lane;
            gld16(Wsrc + fc * 8, &wt[(w * 2 + j) * 512]);
        }
        __syncthreads();
        bf16x8 a[4], b[4];
        const int q = lane >> 4;
        #pragma unroll
        for (int mi = 0; mi < 4; ++mi) {
            int R = wm * 64 + mi * 16 + (lane & 15);
            a[mi] = *reinterpret_cast<const bf16x8*>(&zt[R * 32 + q * 8]);
        }
        #pragma unroll
        for (int ni = 0; ni < 4; ++ni) {
            int R = wn * 64 + ni * 16 + (lane & 15);
            b[ni] = *reinterpret_cast<const bf16x8*>(&wt[R * 32 + q * 8]);
        }
        #pragma unroll
        for (int mi = 0; mi < 4; ++mi)
            #pragma unroll
            for (int ni = 0; ni < 4; ++ni)
                acc[mi][ni] = __builtin_amdgcn_mfma_f32_16x16x32_bf16(a[mi], b[ni], acc[mi][ni], 0, 0, 0);
    }

    #pragma unroll
    for (int mi = 0; mi < 4; ++mi)
        #pragma unroll
        for (int ni = 0; ni < 4; ++ni) {
            int col = colg * 256 + wn * 64 + ni * 16 + (lane & 15);
            #pragma unroll
            for (int r = 0; r < 4; ++r) {
                int row = node0 + wm * 64 + mi * 16 + ((lane >> 4) << 2) + r;
                if (row < Nn)
                    Gout[(size_t)row * 512 + col] = f2f8(acc[mi][ni][r]);
            }
        }
}

// ---------------- edge kernel v5 (fp8 G2) ----------------

__global__ __launch_bounds__(256, 6) void k_edge(const unsigned char* __restrict__ G2,
                                                 const float* __restrict__ attr,
                                                 const int* __restrict__ eu,
                                                 const int* __restrict__ ev,
                                                 const uint4* __restrict__ WaF,
                                                 const float* __restrict__ W2,
                                                 const float* __restrict__ b2,
                                                 const float* __restrict__ logexp,
                                                 float* __restrict__ out, int P) {
    __shared__ __align__(16) unsigned short attrT[64 * 40];
    __shared__ __align__(16) unsigned char gt[64 * 264];
    __shared__ float w2s[256];
    __shared__ int euv[128];
    const int t = threadIdx.x;
    const int lane = t & 63, w = t >> 6;
    const int base = blockIdx.x * 64;

    {
        int e = t >> 2, seg = t & 3;
        int eg = base + e; if (eg >= P) eg = P - 1;
        const float4 f = *reinterpret_cast<const float4*>(attr + (size_t)eg * 16 + seg * 4);
        uint2 o;
        o.x = (unsigned)f2b(f.x) | ((unsigned)f2b(f.y) << 16);
        o.y = (unsigned)f2b(f.z) | ((unsigned)f2b(f.w) << 16);
        *reinterpret_cast<uint2*>(&attrT[e * 40 + seg * 4]) = o;
    }
    if (t < 64) {
        uint2 z0; z0.x = 0x3f80u; z0.y = 0u;
        *reinterpret_cast<uint2*>(&attrT[t * 40 + 16]) = z0;
        uint2 z1; z1.x = 0u; z1.y = 0u;
        *reinterpret_cast<uint2*>(&attrT[t * 40 + 20]) = z1;
        uint4 z2; z2.x = z2.y = z2.z = z2.w = 0u;
        *reinterpret_cast<uint4*>(&attrT[t * 40 + 24]) = z2;
    }
    if (t < 128) {
        int e = t >> 1;
        int eg = base + e; if (eg >= P) eg = P - 1;
        euv[t] = (t & 1) ? ev[eg] : eu[eg];
    }
    w2s[t] = W2[t];
    __syncthreads();

    const int el = lane & 15, q = lane >> 4;
    const int grow = w * 16 + el;
    const bf16x8 bfrag = *reinterpret_cast<const bf16x8*>(&attrT[grow * 40 + q * 8]);

    float s = 0.f;
    #pragma unroll
    for (int p = 0; p < 2; ++p) {
        {
            const int sub = lane >> 4, c = lane & 15;
            #pragma unroll
            for (int i = 0; i < 4; ++i) {
                int le = w * 16 + i * 4 + sub;
                int u = euv[2 * le], v = euv[2 * le + 1];
                uint2 a = *reinterpret_cast<const uint2*>(G2 + (size_t)u * 512 + p * 128 + c * 8);
                uint2 b = *reinterpret_cast<const uint2*>(G2 + (size_t)v * 512 + 256 + p * 128 + c * 8);
                *reinterpret_cast<uint2*>(&gt[le * 264 + c * 8]) = a;
                *reinterpret_cast<uint2*>(&gt[le * 264 + 128 + c * 8]) = b;
            }
        }
        #pragma unroll
        for (int m = 0; m < 8; ++m) {
            const int mi = p * 8 + m;
            const bf16x8 af = *reinterpret_cast<const bf16x8*>(&WaF[mi * 64 + lane]);
            f32x4 acc = __builtin_amdgcn_mfma_f32_16x16x32_bf16(af, bfrag, (f32x4){0.f,0.f,0.f,0.f}, 0, 0, 0);
            const unsigned gu4 = *reinterpret_cast<const unsigned*>(&gt[grow * 264 + m * 16 + q * 4]);
            const unsigned gv4 = *reinterpret_cast<const unsigned*>(&gt[grow * 264 + 128 + m * 16 + q * 4]);
            const float4 w2v = *reinterpret_cast<const float4*>(&w2s[mi * 16 + q * 4]);
            f32x2 ulo = __builtin_amdgcn_cvt_pk_f32_fp8(gu4, false);
            f32x2 uhi = __builtin_amdgcn_cvt_pk_f32_fp8(gu4, true);
            f32x2 vlo = __builtin_amdgcn_cvt_pk_f32_fp8(gv4, false);
            f32x2 vhi = __builtin_amdgcn_cvt_pk_f32_fp8(gv4, true);
            float y0 = acc[0] + ulo.x + vlo.x;
            float y1 = acc[1] + ulo.y + vlo.y;
            float y2 = acc[2] + uhi.x + vhi.x;
            float y3 = acc[3] + uhi.y + vhi.y;
            s += (y0 > 0.f ? y0 : 0.f) * w2v.x;
            s += (y1 > 0.f ? y1 : 0.f) * w2v.y;
            s += (y2 > 0.f ? y2 : 0.f) * w2v.z;
            s += (y3 > 0.f ? y3 : 0.f) * w2v.w;
        }
        if (p == 0) __syncthreads();
    }
    s += __shfl_xor(s, 16);
    s += __shfl_xor(s, 32);
    int eg = base + grow;
    if (q == 0 && eg < P)
        out[eg] = logexp[eg] + b2[0] + s;
}

// ---------------- launch ----------------

extern "C" void kernel_launch(void* const* d_in, const int* in_sizes, int n_in,
                              void* d_out, int out_size, void* d_ws, size_t ws_size,
                              hipStream_t stream) {
    const float* x      = (const float*)d_in[0];
    const int*   eidx   = (const int*)d_in[1];
    const int*   eu     = (const int*)d_in[2];
    const int*   ev     = (const int*)d_in[3];
    const float* attr   = (const float*)d_in[4];
    const float* logexp = (const float*)d_in[5];
    const float* Wl1    = (const float*)d_in[6];
    const float* bl1    = (const float*)d_in[7];
    const float* Wr1    = (const float*)d_in[8];
    const float* Wl2    = (const float*)d_in[9];
    const float* bl2    = (const float*)d_in[10];
    const float* Wr2    = (const float*)d_in[11];
    const float* W1     = (const float*)d_in[12];
    const float* b1     = (const float*)d_in[13];
    const float* W2     = (const float*)d_in[14];
    const float* b2     = (const float*)d_in[15];
    float* out = (float*)d_out;

    const int N = in_sizes[0] / 128;
    const int E = in_sizes[1] / 2;
    const int P = in_sizes[2];
    const int* src = eidx;
    const int* dst = eidx + E;

    char* ws = (char*)d_ws;
    size_t off = 0;
    auto alloc = [&](size_t bytes) -> void* {
        off = (off + 255) & ~(size_t)255;
        void* p = ws + off;
        off += bytes;
        return p;
    };
    int* row_ptr = (int*)alloc((size_t)(N + 1) * 4);
    int* cursor  = (int*)alloc((size_t)N * 4);
    int* bucket  = (int*)alloc((size_t)E * 4);
    unsigned short* h1 = (unsigned short*)alloc((size_t)N * 256 * 2);
    unsigned short* h2 = (unsigned short*)alloc((size_t)N * 256 * 2);
    char* shared_base = (char*)alloc((size_t)N * 512 * 2);
    unsigned short* xb   = (unsigned short*)shared_base;                         // N*128 bf16
    unsigned short* agg1 = (unsigned short*)(shared_base + (size_t)N * 128 * 2); // N*128 bf16
    unsigned short* agg2 = (unsigned short*)(shared_base + (size_t)N * 256 * 2); // N*256 bf16
    unsigned char*  G2f8 = (unsigned char*)shared_base;                          // N*512 bytes
    unsigned char* xf8  = (unsigned char*)alloc((size_t)N * 128);
    unsigned char* h1f8 = (unsigned char*)alloc((size_t)N * 256);
    unsigned short* Wc1  = (unsigned short*)alloc((size_t)65536 * 2);
    unsigned short* Wc2  = (unsigned short*)alloc((size_t)131072 * 2);
    unsigned short* W1g  = (unsigned short*)alloc((size_t)131072 * 2);
    unsigned short* WaF  = (unsigned short*)alloc((size_t)8192 * 2);

    hipMemsetAsync(cursor, 0, (size_t)N * 4, stream);
    const int nbCount = (E + 255) / 256;
    const int nbConv  = (65536 + 131072 + 131072 + 8192 + 255) / 256;
    const int nbX     = (N * 64 + 255) / 256;
    k_setup<<<nbCount + nbConv + nbX, 256, 0, stream>>>(
        dst, cursor, E, Wl1, Wr1, Wl2, Wr2, W1, b1, Wc1, Wc2, W1g, WaF,
        x, xb, xf8, N * 128, nbCount, nbConv);
    k_scan<<<1, 1024, 0, stream>>>(cursor, row_ptr, N);
    k_scatter<<<(E + 255) / 256, 256, 0, stream>>>(src, dst, cursor, bucket, E);

    k_agg_x<<<(N + 3) / 4, 256, 0, stream>>>(xf8, row_ptr, bucket, agg1, N);
    k_conv_gemm<<<(N + 127) / 128, 512, 0, stream>>>(agg1, xb, Wc1, bl1, h1, h1f8, N, 128);
    k_agg_h<<<(N + 3) / 4, 256, 0, stream>>>(h1f8, row_ptr, bucket, agg2, N);
    k_conv_gemm<<<(N + 127) / 128, 512, 0, stream>>>(agg2, h1, Wc2, bl2, h2, (unsigned char*)nullptr, N, 256);

    dim3 gg((N + 127) / 128, 2);
    k_gemm_g<<<gg, 512, 0, stream>>>(h2, W1g, G2f8, N);
    k_edge<<<(P + 63) / 64, 256, 0, stream>>>(G2f8, attr, eu, ev, (const uint4*)WaF,
                                              W2, b2, logexp, out, P);
}